// Round 4
// baseline (7561585.938 us; speedup 1.0000x reference)
//
#include <hip/hip_runtime.h>

typedef __attribute__((ext_vector_type(8))) short short8;
typedef __attribute__((ext_vector_type(4))) float f32x4;

#define B_   64
#define S_   512
#define V_   1400
#define VP_  1408
#define H_   256
#define G4_  1024
#define NC_  128
#define CH_  64    // time-chunk length (8 chunks of 64 steps)

__device__ __forceinline__ unsigned short f2bf(float f) {
    unsigned u = __builtin_bit_cast(unsigned, f);
    u += 0x7FFFu + ((u >> 16) & 1u);
    return (unsigned short)(u >> 16);
}
__device__ __forceinline__ float bf2f(unsigned short h) {
    unsigned u = ((unsigned)h) << 16;
    return __builtin_bit_cast(float, u);
}
__device__ __forceinline__ float fsig(float x) {
    x = fminf(fmaxf(x, -40.f), 40.f);
    float e = __builtin_amdgcn_exp2f(x * -1.44269504f);
    return __builtin_amdgcn_rcpf(1.0f + e);
}
__device__ __forceinline__ float ftanh(float x) {
    x = fminf(fmaxf(x, -40.f), 40.f);
    float e = __builtin_amdgcn_exp2f(x * 2.88539008f);
    return 1.0f - 2.0f * __builtin_amdgcn_rcpf(e + 1.0f);
}

// ---- IC-coherent (cross-XCD) primitives — proven fallback path ----
__device__ __forceinline__ short8 gload16_sc1(const unsigned short* p) {
    short8 r;
    asm volatile("global_load_dwordx4 %0, %1, off sc1"
                 : "=&v"(r) : "v"((unsigned long long)p));
    return r;
}
__device__ __forceinline__ void gstore_short_sc1(unsigned short* p, unsigned v) {
    asm volatile("global_store_short %0, %1, off sc1"
                 :: "v"((unsigned long long)p), "v"(v));
}
// ---- L2-local (same-XCD) primitives — fast path ----
// sc0 on a load = classic GLC: serve from the coherent point (the XCD's L2),
// bypass L1. Peer data arrives in that same L2 via write-through plain stores.
__device__ __forceinline__ short8 gload16_sc0(const unsigned short* p) {
    short8 r;
    asm volatile("global_load_dwordx4 %0, %1, off sc0"
                 : "=&v"(r) : "v"((unsigned long long)p));
    return r;
}
__device__ __forceinline__ unsigned gpoll_sc0(const unsigned int* p) {
    unsigned r;   // early-clobber: output must NOT alias the address pair
    asm volatile("global_load_dword %0, %1, off sc0\n\ts_waitcnt vmcnt(0)"
                 : "=&v"(r) : "v"((unsigned long long)p));
    return r;
}
__device__ __forceinline__ void gstore_short_plain(unsigned short* p, unsigned v) {
    asm volatile("global_store_short %0, %1, off"
                 :: "v"((unsigned long long)p), "v"(v));
}
__device__ __forceinline__ void gatomic_add_plain(unsigned int* p, unsigned v) {
    // plain global_atomic executes in the issuing XCD's TCC (L2)
    asm volatile("global_atomic_add %0, %1, off"
                 :: "v"((unsigned long long)p), "v"(v));
}

// cnt zone layout (ints): step counters (chunk*8+grp)*64  [0,4096)
//                         rdy[chunk] at 4096+chunk*64     [4096,4608)
//                         xpub[32]   at 4608              [4608,4640)
#define CNT_ZONE_ 5120

// ---------------------------------------------------------------- K0: prep
__global__ void k0_prep(const float* __restrict__ emb,
                        const float* __restrict__ Wa1, const float* __restrict__ Wa2,
                        const float* __restrict__ Wd1, const float* __restrict__ Wd2,
                        const float* __restrict__ U1,  const float* __restrict__ U2,
                        const float* __restrict__ ba1, const float* __restrict__ bu1,
                        const float* __restrict__ ba2, const float* __restrict__ bu2,
                        const float* __restrict__ Wb,
                        unsigned short* __restrict__ embT, unsigned short* __restrict__ Wg,
                        unsigned short* __restrict__ Wd,   unsigned short* __restrict__ Ub,
                        unsigned short* __restrict__ Wbb,  float* __restrict__ bg,
                        unsigned int* __restrict__ cnt) {
    int tid = blockIdx.x * blockDim.x + threadIdx.x;
    int np = gridDim.x * blockDim.x;
    for (int i = tid; i < 256 * VP_; i += np) {
        int n = i / VP_, k = i - n * VP_;
        embT[i] = (k < V_) ? f2bf(emb[k * H_ + n]) : (unsigned short)0;
    }
    for (int i = tid; i < G4_ * H_; i += np) {
        Wg[i] = f2bf(Wa1[i]); Wg[G4_ * H_ + i] = f2bf(Wa2[i]);
        Ub[i] = f2bf(U1[i]);  Ub[G4_ * H_ + i] = f2bf(U2[i]);
    }
    for (int i = tid; i < H_ * H_; i += np) {
        Wd[i] = f2bf(Wd1[i]); Wd[H_ * H_ + i] = f2bf(Wd2[i]); Wbb[i] = f2bf(Wb[i]);
    }
    for (int i = tid; i < G4_; i += np) {
        bg[i] = ba1[i] + bu1[i]; bg[G4_ + i] = ba2[i] + bu2[i];
    }
    for (int i = tid; i < CNT_ZONE_; i += np) cnt[i] = 0;   // sync zone (re-zeroed every run)
}

// ---------------------------------------------------------------- K1: embedded = inputs @ emb
__global__ __launch_bounds__(512, 2) void k1_embed(const float* __restrict__ inputs,
                                                   const unsigned short* __restrict__ embT,
                                                   unsigned short* __restrict__ embB) {
    const int tid = threadIdx.x;
    const int w = tid >> 6, ln = tid & 63, q = ln >> 4, l16 = ln & 15;
    const int mt = w >> 2, ng = (w & 3) * 4;
    const int Rbase = blockIdx.x * 32 + mt * 16;
    const float* arow = inputs + (long)(Rbase + l16) * V_;

    f32x4 acc[4];
    #pragma unroll
    for (int i = 0; i < 4; ++i) acc[i] = (f32x4){0.f, 0.f, 0.f, 0.f};

    for (int kt = 0; kt < 44; ++kt) {
        int k0 = kt * 32 + q * 8;
        short8 af;
        if (kt == 43 && q == 3) {
            #pragma unroll
            for (int j = 0; j < 8; ++j) af[j] = 0;
        } else {
            f32x4 x0 = *(const f32x4*)(arow + k0);
            f32x4 x1 = *(const f32x4*)(arow + k0 + 4);
            #pragma unroll
            for (int j = 0; j < 4; ++j) { af[j] = (short)f2bf(x0[j]); af[4 + j] = (short)f2bf(x1[j]); }
        }
        #pragma unroll
        for (int i = 0; i < 4; ++i) {
            short8 bf = *(const short8*)(embT + (long)((ng + i) * 16 + l16) * VP_ + k0);
            acc[i] = __builtin_amdgcn_mfma_f32_16x16x32_bf16(af, bf, acc[i], 0, 0, 0);
        }
    }
    #pragma unroll
    for (int i = 0; i < 4; ++i) {
        int col = (ng + i) * 16 + l16;
        #pragma unroll
        for (int j = 0; j < 4; ++j) {
            int R = Rbase + 4 * q + j;
            embB[(long)R * H_ + col] = f2bf(acc[i][j]);
        }
    }
}

// ---------------------------------------------------------------- K2: P chunk = embedded @ [U1;U2]^T + bg
__global__ __launch_bounds__(512, 2) void k2_pre(const unsigned short* __restrict__ embB,
                                                 const unsigned short* __restrict__ Ub,
                                                 const float* __restrict__ bg,
                                                 float* __restrict__ P, int t0) {
    const int tid = threadIdx.x;
    const int w = tid >> 6, ln = tid & 63, q = ln >> 4, l16 = ln & 15;
    const int rbase = blockIdx.x * 32;  // local row' in chunk, 0..4095

    short8 af[2][8];
    #pragma unroll
    for (int mt = 0; mt < 2; ++mt)
        #pragma unroll
        for (int kt = 0; kt < 8; ++kt) {
            int rp = rbase + mt * 16 + l16;
            int rg = t0 * 64 + rp;
            int b = rg & 63, s = rg >> 6;
            af[mt][kt] = *(const short8*)(embB + ((long)b * S_ + s) * H_ + kt * 32 + q * 8);
        }

    for (int i = 0; i < 16; ++i) {
        int nt2 = w * 16 + i;          // global gate-col tile 0..127
        int l = nt2 >> 6;
        int gcol = (nt2 & 63) * 16 + l16;   // col within lstm, 0..1023
        float bias = bg[nt2 * 16 + l16];
        short8 bf[8];
        #pragma unroll
        for (int kt = 0; kt < 8; ++kt)
            bf[kt] = *(const short8*)(Ub + (long)(nt2 * 16 + l16) * H_ + kt * 32 + q * 8);
        #pragma unroll
        for (int mt = 0; mt < 2; ++mt) {
            f32x4 acc = (f32x4){bias, bias, bias, bias};
            #pragma unroll
            for (int kt = 0; kt < 8; ++kt)
                acc = __builtin_amdgcn_mfma_f32_16x16x32_bf16(af[mt][kt], bf[kt], acc, 0, 0, 0);
            int rp0 = rbase + mt * 16;
            float* dst = P + ((long)l * (CH_ * 64) + rp0 + 4 * q) * G4_ + gcol;
            #pragma unroll
            for (int j = 0; j < 4; ++j) dst[(long)j * G4_] = acc[j];
        }
    }
}

// ---------------------------------------------------------------- K3: time-LSTM chunk (64 steps)
// Round-9: XCD-local fast path, re-attempted with the three round-8 hazards fixed:
//   (1) ALL hot sync cells 256B-spaced and single-writer-XCD (was 16B spacing ->
//       cross-XCD dirty-line clobbering -> possible counter rollback deadlock).
//   (2) every asm load uses early-clobber "=&v" (was "=v": poll output could
//       alias its address pair inside the spin loop -> infinite spin).
//   (3) XCC id via __builtin_amdgcn_s_getreg (compile-safe).
//   All polls are iteration-BOUNDED: a broken protocol now finishes with wrong
//   data (diagnosable: counters + absmax) instead of hanging the harness.
// Fast path (all 4 col-blocks of a group verified same-XCD): plain write-through
// stores + plain L2 atomics + sc0 (GLC, L1-bypass, L2-served) loads; per-WAVE
// posting, no in-loop barriers. Fallback: round-7 proven IC/sc1 protocol.
__global__ __launch_bounds__(256, 1) void k3_lstm(const float* __restrict__ ts,
                                                  const unsigned short* __restrict__ W, // Wg || Wd
                                                  const float* __restrict__ bd1,
                                                  const float* __restrict__ bd2,
                                                  const float* __restrict__ P,
                                                  unsigned short* __restrict__ out1,
                                                  unsigned short* __restrict__ out2,
                                                  float* __restrict__ cst,
                                                  unsigned short* __restrict__ cx,
                                                  unsigned int* __restrict__ cnt,
                                                  int t0) {
    __shared__ float ts_lds[16][CH_];

    const int tid = threadIdx.x;
    const int w = tid >> 6, ln = tid & 63, q = ln >> 4, l16 = ln & 15;
    const int bid = blockIdx.x;
    const int chunk = t0 >> 6;

    // -------- XCD discovery (IC-scope handshake, once per launch) ------------
    // hwreg(HW_REG_XCC_ID=20, offset 0, size 32) -> imm = 20 | (31<<11) = 63508
    const int myx = (int)__builtin_amdgcn_s_getreg(63508);
    unsigned int* rdy  = cnt + 4096 + chunk * 64;
    int*          xpub = (int*)(cnt + 4608);
    if (tid == 0) {
        __hip_atomic_store(&xpub[bid], myx, __ATOMIC_RELAXED, __HIP_MEMORY_SCOPE_AGENT);
        __hip_atomic_fetch_add(rdy, 1u, __ATOMIC_RELEASE, __HIP_MEMORY_SCOPE_AGENT);
    }
    unsigned hs_it = 0;
    while (__hip_atomic_load(rdy, __ATOMIC_ACQUIRE, __HIP_MEMORY_SCOPE_AGENT) < 32u
           && ++hs_it < (1u << 20))
        __builtin_amdgcn_s_sleep(2);
    int xv[32];
    #pragma unroll
    for (int i = 0; i < 32; ++i)
        xv[i] = __hip_atomic_load(&xpub[i], __ATOMIC_RELAXED, __HIP_MEMORY_SCOPE_AGENT);
    unsigned okA = 1, inr = 1, mask = 0;
    #pragma unroll
    for (int g = 0; g < 8; ++g)
        okA &= (unsigned)((xv[g] == xv[g + 8]) & (xv[g] == xv[g + 16]) & (xv[g] == xv[g + 24]));
    #pragma unroll
    for (int i = 0; i < 32; ++i) {
        inr &= (unsigned)((unsigned)xv[i] < 8u);
        mask |= 1u << ((unsigned)xv[i] & 31u);
    }
    const bool fast = okA && inr && (mask == 0xFFu) && (hs_it < (1u << 20));

    // -------- role decode (identical for both paths; any bijection is valid) --
    const int grp = bid & 7, cg = bid >> 3;    // mapping A: {g,g+8,g+16,g+24} co-XCD
    const int l = grp >> 2, m = grp & 3, b0 = m * 16;
    const int hc0 = cg * 64 + w * 16;
    const int mycol = hc0 + l16;
    unsigned int* cell = cnt + (chunk * 8 + grp) * 64;   // 256B-spaced, per-chunk
    unsigned short* outp = l ? out2 : out1;
    const float bdv = (l ? bd2 : bd1)[mycol];

    for (int i = tid; i < 16 * CH_; i += 256) {
        int r = i >> 6, cc = i & (CH_ - 1);
        ts_lds[r][cc] = ts[(b0 + r) * S_ + t0 + cc];
    }

    // -------- register/AGPR-resident weights (loaded once per launch) --------
    short8 wg[4][8];
    short8 wd[8];
    #pragma unroll
    for (int g = 0; g < 4; ++g)
        #pragma unroll
        for (int kt = 0; kt < 8; ++kt)
            wg[g][kt] = *(const short8*)(W + ((long)(l * G4_ + g * H_ + mycol)) * H_ + kt * 32 + q * 8);
    #pragma unroll
    for (int kt = 0; kt < 8; ++kt)
        wd[kt] = *(const short8*)(W + (long)2 * G4_ * H_ + ((long)(l * H_ + mycol)) * H_ + kt * 32 + q * 8);

    float cf[4];
    if (t0 == 0) {
        cf[0] = cf[1] = cf[2] = cf[3] = 0.f;
    } else {
        #pragma unroll
        for (int j = 0; j < 4; ++j)
            cf[j] = cst[(long)(l * 4 + m) * 4096 + (4 * q + j) * 256 + mycol];
    }
    __syncthreads();   // ts_lds ready

    const float* Pbase = P + ((long)l * (CH_ * 64) + b0) * G4_;

    if (fast) {
        // ================= FAST: same-XCD, L2-scope protocol =================
        #pragma unroll 1
        for (int t = 0; t < CH_; ++t) {
            const int gt = t0 + t;

            // P(t) loads first (peer-independent; latency hides under the poll)
            float pv[4][4];
            #pragma unroll
            for (int g = 0; g < 4; ++g)
                #pragma unroll
                for (int j = 0; j < 4; ++j)
                    pv[g][j] = Pbase[((long)t * 64 + 4 * q + j) * G4_ + g * H_ + mycol];
            asm volatile("" ::: "memory");

            {   // wait: all 16 waves of this group posted step t-1 (bounded)
                unsigned tgt = 16u * (unsigned)t, v, it = 0;
                do { v = gpoll_sc0(cell); }
                while (v < tgt && ++it < (1u << 18));
            }
            __builtin_amdgcn_sched_barrier(0);

            short8 ha[8], ca[8];
            if (gt == 0) {
                #pragma unroll
                for (int kt = 0; kt < 8; ++kt) {
                    #pragma unroll
                    for (int j = 0; j < 8; ++j) { ha[kt][j] = 0; ca[kt][j] = 0; }
                }
            } else {
                const unsigned short* crow = cx + ((long)(((gt - 1) & 1) * 8 + grp)) * 4096 + l16 * 256 + q * 8;
                const unsigned short* hrow = outp + ((long)(b0 + l16) * S_ + (gt - 1)) * H_ + q * 8;
                #pragma unroll
                for (int kt = 0; kt < 8; ++kt) ca[kt] = gload16_sc0(crow + kt * 32);
                #pragma unroll
                for (int kt = 0; kt < 8; ++kt) ha[kt] = gload16_sc0(hrow + kt * 32);
            }
            asm volatile("s_waitcnt vmcnt(8)" ::: "memory");   // ca complete
            __builtin_amdgcn_sched_barrier(0);

            f32x4 dacc = (f32x4){bdv, bdv, bdv, bdv};
            #pragma unroll
            for (int kt = 0; kt < 8; ++kt)
                dacc = __builtin_amdgcn_mfma_f32_16x16x32_bf16(ca[kt], wd[kt], dacc, 0, 0, 0);

            asm volatile("s_waitcnt vmcnt(0)" ::: "memory");   // ha complete
            __builtin_amdgcn_sched_barrier(0);

            f32x4 gacc[4];
            #pragma unroll
            for (int g = 0; g < 4; ++g) {
                gacc[g] = (f32x4){pv[g][0], pv[g][1], pv[g][2], pv[g][3]};
                #pragma unroll
                for (int kt = 0; kt < 8; ++kt)
                    gacc[g] = __builtin_amdgcn_mfma_f32_16x16x32_bf16(ha[kt], wg[g][kt], gacc[g], 0, 0, 0);
            }

            #pragma unroll
            for (int j = 0; j < 4; ++j) {
                int r = 4 * q + j;
                float tv = ts_lds[r][t];
                float cs1 = ftanh(dacc[j]);
                float cadj = cf[j] + cs1 * (tv - 1.0f);
                float fg = fsig(gacc[0][j]), ig = fsig(gacc[1][j]);
                float og = fsig(gacc[2][j]), ct = fsig(gacc[3][j]);
                float cn = fg * cadj + ig * ct;
                float hn = og * ftanh(cn);
                cf[j] = cn;
                gstore_short_plain(outp + ((long)(b0 + r) * S_ + gt) * H_ + mycol, (unsigned)f2bf(hn));
                gstore_short_plain(cx + ((long)((gt & 1) * 8 + grp)) * 4096 + r * 256 + mycol, (unsigned)f2bf(cn));
            }
            asm volatile("s_waitcnt vmcnt(0)" ::: "memory");   // stores ack'd at L2
            if (ln == 0) gatomic_add_plain(cell, 1u);          // per-wave post (16/step)
        }
    } else {
        // ============ FALLBACK: proven IC-scope protocol (round-7) ============
        #pragma unroll 1
        for (int t = 0; t < CH_; ++t) {
            const int gt = t0 + t;

            float pv[4][4];
            #pragma unroll
            for (int g = 0; g < 4; ++g)
                #pragma unroll
                for (int j = 0; j < 4; ++j)
                    pv[g][j] = Pbase[((long)t * 64 + 4 * q + j) * G4_ + g * H_ + mycol];
            asm volatile("" ::: "memory");

            {
                unsigned tgt = 4u * (unsigned)t, it = 0;
                while (__hip_atomic_load(cell, __ATOMIC_RELAXED, __HIP_MEMORY_SCOPE_AGENT) < tgt
                       && ++it < (1u << 18))
                    __builtin_amdgcn_s_sleep(1);
            }

            short8 ha[8], ca[8];
            if (gt == 0) {
                #pragma unroll
                for (int kt = 0; kt < 8; ++kt) {
                    #pragma unroll
                    for (int j = 0; j < 8; ++j) { ha[kt][j] = 0; ca[kt][j] = 0; }
                }
            } else {
                const unsigned short* crow = cx + ((long)(((gt - 1) & 1) * 8 + grp)) * 4096 + l16 * 256 + q * 8;
                const unsigned short* hrow = outp + ((long)(b0 + l16) * S_ + (gt - 1)) * H_ + q * 8;
                #pragma unroll
                for (int kt = 0; kt < 8; ++kt) ca[kt] = gload16_sc1(crow + kt * 32);
                #pragma unroll
                for (int kt = 0; kt < 8; ++kt) ha[kt] = gload16_sc1(hrow + kt * 32);
            }
            asm volatile("s_waitcnt vmcnt(8)" ::: "memory");
            __builtin_amdgcn_sched_barrier(0);

            f32x4 dacc = (f32x4){bdv, bdv, bdv, bdv};
            #pragma unroll
            for (int kt = 0; kt < 8; ++kt)
                dacc = __builtin_amdgcn_mfma_f32_16x16x32_bf16(ca[kt], wd[kt], dacc, 0, 0, 0);

            asm volatile("s_waitcnt vmcnt(0)" ::: "memory");
            __builtin_amdgcn_sched_barrier(0);

            f32x4 gacc[4];
            #pragma unroll
            for (int g = 0; g < 4; ++g) {
                gacc[g] = (f32x4){pv[g][0], pv[g][1], pv[g][2], pv[g][3]};
                #pragma unroll
                for (int kt = 0; kt < 8; ++kt)
                    gacc[g] = __builtin_amdgcn_mfma_f32_16x16x32_bf16(ha[kt], wg[g][kt], gacc[g], 0, 0, 0);
            }

            #pragma unroll
            for (int j = 0; j < 4; ++j) {
                int r = 4 * q + j;
                float tv = ts_lds[r][t];
                float cs1 = ftanh(dacc[j]);
                float cadj = cf[j] + cs1 * (tv - 1.0f);
                float fg = fsig(gacc[0][j]), ig = fsig(gacc[1][j]);
                float og = fsig(gacc[2][j]), ct = fsig(gacc[3][j]);
                float cn = fg * cadj + ig * ct;
                float hn = og * ftanh(cn);
                cf[j] = cn;
                gstore_short_sc1(outp + ((long)(b0 + r) * S_ + gt) * H_ + mycol, (unsigned)f2bf(hn));
                gstore_short_sc1(cx + ((long)((gt & 1) * 8 + grp)) * 4096 + r * 256 + mycol, (unsigned)f2bf(cn));
            }
            asm volatile("s_waitcnt vmcnt(0)" ::: "memory");
            __syncthreads();
            if (tid == 0) atomicAdd(cell, 1u);
        }
    }

    // persist fp32 c for next chunk
    #pragma unroll
    for (int j = 0; j < 4; ++j)
        cst[(long)(l * 4 + m) * 4096 + (4 * q + j) * 256 + mycol] = cf[j];
}

// ---------------------------------------------------------------- K4a: scores + softmax -> alpha
__global__ __launch_bounds__(512) void k4a_alpha(const unsigned short* __restrict__ out1,
                                                 const float* __restrict__ wa,
                                                 float* __restrict__ alpha) {
    __shared__ float sc[512];
    __shared__ float red[512];
    const int b = blockIdx.x, tid = threadIdx.x;
    const int w = tid >> 6, ln = tid & 63;
    f32x4 wv = *(const f32x4*)(wa + ln * 4);
    for (int i = 0; i < 64; ++i) {
        int s = w * 64 + i;
        const unsigned short* row = out1 + ((long)b * S_ + s) * H_ + ln * 4;
        float d = bf2f(row[0]) * wv[0] + bf2f(row[1]) * wv[1] +
                  bf2f(row[2]) * wv[2] + bf2f(row[3]) * wv[3];
        #pragma unroll
        for (int off = 32; off; off >>= 1) d += __shfl_xor(d, off);
        if (ln == 0) sc[s] = d;
    }
    __syncthreads();
    float v = sc[tid];
    red[tid] = v;
    for (int st = 256; st; st >>= 1) {
        __syncthreads();
        if (tid < st) red[tid] = fmaxf(red[tid], red[tid + st]);
    }
    __syncthreads();
    float M = red[0];
    __syncthreads();
    float e = __builtin_amdgcn_exp2f((v - M) * 1.44269504f);
    red[tid] = e;
    for (int st = 256; st; st >>= 1) {
        __syncthreads();
        if (tid < st) red[tid] += red[tid + st];
    }
    __syncthreads();
    alpha[b * S_ + tid] = e * __builtin_amdgcn_rcpf(red[0]);
}

// ---------------------------------------------------------------- K4b: Beta=tanh(out2@Wb^T); ctx = sum_s emb*Beta*alpha
__global__ __launch_bounds__(512, 2) void k4b_ctx(const unsigned short* __restrict__ out2,
                                                  const unsigned short* __restrict__ Wbb,
                                                  const unsigned short* __restrict__ embB,
                                                  const float* __restrict__ alpha,
                                                  float* __restrict__ ctx) {
    __shared__ float cbuf[32][256];
    const int b = blockIdx.x, tid = threadIdx.x;
    const int w = tid >> 6, ln = tid & 63, q = ln >> 4, l16 = ln & 15;

    float cp[16];
    #pragma unroll
    for (int nt = 0; nt < 16; ++nt) cp[nt] = 0.f;

    for (int i = 0; i < 4; ++i) {
        int mt = w * 4 + i;
        short8 af[8];
        #pragma unroll
        for (int kt = 0; kt < 8; ++kt)
            af[kt] = *(const short8*)(out2 + ((long)b * S_ + mt * 16 + l16) * H_ + kt * 32 + q * 8);
        float al[4];
        #pragma unroll
        for (int j = 0; j < 4; ++j) al[j] = alpha[b * S_ + mt * 16 + 4 * q + j];
        for (int nt = 0; nt < 16; ++nt) {
            f32x4 acc = (f32x4){0.f, 0.f, 0.f, 0.f};
            #pragma unroll
            for (int kt = 0; kt < 8; ++kt) {
                short8 bf = *(const short8*)(Wbb + (long)(nt * 16 + l16) * H_ + kt * 32 + q * 8);
                acc = __builtin_amdgcn_mfma_f32_16x16x32_bf16(af[kt], bf, acc, 0, 0, 0);
            }
            #pragma unroll
            for (int j = 0; j < 4; ++j) {
                int s = mt * 16 + 4 * q + j;
                float beta = ftanh(acc[j]);
                float ev = bf2f(embB[((long)b * S_ + s) * H_ + nt * 16 + l16]);
                cp[nt] += beta * al[j] * ev;
            }
        }
    }
    #pragma unroll
    for (int nt = 0; nt < 16; ++nt) cbuf[w * 4 + q][nt * 16 + l16] = cp[nt];
    __syncthreads();
    if (tid < 256) {
        float sum = 0.f;
        for (int i = 0; i < 32; ++i) sum += cbuf[i][tid];
        ctx[b * H_ + tid] = sum;
    }
}

// ---------------------------------------------------------------- K4c: out = ctx @ W_out^T
__global__ void k4c_out(const float* __restrict__ ctx, const float* __restrict__ Wout,
                        float* __restrict__ out) {
    int b = blockIdx.x, n = threadIdx.x;
    const f32x4* cr = (const f32x4*)(ctx + b * H_);
    const f32x4* wr = (const f32x4*)(Wout + n * H_);
    float acc = 0.f;
    #pragma unroll 8
    for (int i = 0; i < 64; ++i) {
        f32x4 c = cr[i], ww = wr[i];
        acc += c[0] * ww[0] + c[1] * ww[1] + c[2] * ww[2] + c[3] * ww[3];
    }
    out[b * NC_ + n] = acc;
}

// ---------------------------------------------------------------- launch
extern "C" void kernel_launch(void* const* d_in, const int* in_sizes, int n_in,
                              void* d_out, int out_size, void* d_ws, size_t ws_size,
                              hipStream_t stream) {
    (void)in_sizes; (void)n_in; (void)out_size; (void)ws_size;
    const float* inputs = (const float*)d_in[0];
    const float* tsp    = (const float*)d_in[1];
    const float* emb    = (const float*)d_in[2];
    const float* Wa1 = (const float*)d_in[3];  const float* ba1 = (const float*)d_in[4];
    const float* U1  = (const float*)d_in[5];  const float* bu1 = (const float*)d_in[6];
    const float* Wd1 = (const float*)d_in[7];  const float* bd1 = (const float*)d_in[8];
    const float* Wa2 = (const float*)d_in[9];  const float* ba2 = (const float*)d_in[10];
    const float* U2  = (const float*)d_in[11]; const float* bu2 = (const float*)d_in[12];
    const float* Wd2 = (const float*)d_in[13]; const float* bd2 = (const float*)d_in[14];
    const float* wa  = (const float*)d_in[15];
    const float* Wb  = (const float*)d_in[16];
    const float* Wout = (const float*)d_in[17];
    float* out = (float*)d_out;

    // Workspace map (round-9: cnt zone grown to 20,480B — 256B-spaced counters).
    char* ws = (char*)d_ws;
    unsigned short* embT = (unsigned short*)(ws + 0);            //    720,896
    unsigned short* Wg   = (unsigned short*)(ws + 720896);       //  1,048,576 (Wd must follow)
    unsigned short* Wd   = (unsigned short*)(ws + 1769472);      //    262,144
    unsigned short* Ub   = (unsigned short*)(ws + 2031616);      //  1,048,576
    unsigned short* Wbb  = (unsigned short*)(ws + 3080192);      //    131,072
    float*          bgp  = (float*)(ws + 3211264);               //      8,192
    unsigned short* embB = (unsigned short*)(ws + 3219456);      // 16,777,216
    float*          P    = (float*)(ws + 19996672);              // 33,554,432 (64-step chunk)
    unsigned short* out1 = (unsigned short*)(ws + 53551104);     // 16,777,216
    unsigned short* out2 = (unsigned short*)(ws + 70328320);     // 16,777,216
    unsigned short* cx   = (unsigned short*)(ws + 87105536);     //    131,072 ([2 parity][8 grp][16][256] bf16)
    float*          cst  = (float*)(ws + 87236608);              //    131,072
    float*          alp  = (float*)(ws + 87367680);              //    131,072
    float*          ctx  = (float*)(ws + 87498752);              //     65,536
    unsigned int*   cnt  = (unsigned int*)(ws + 87564288);       //     20,480
    // total: 87,584,768 bytes (~83.5 MiB)

    hipLaunchKernelGGL(k0_prep, dim3(256), dim3(256), 0, stream,
                       emb, Wa1, Wa2, Wd1, Wd2, U1, U2, ba1, bu1, ba2, bu2, Wb,
                       embT, Wg, Wd, Ub, Wbb, bgp, cnt);
    hipLaunchKernelGGL(k1_embed, dim3(1024), dim3(512), 0, stream, inputs, embT, embB);
    for (int c = 0; c < 8; ++c) {
        hipLaunchKernelGGL(k2_pre, dim3(128), dim3(512), 0, stream, embB, Ub, bgp, P, c * CH_);
        hipLaunchKernelGGL(k3_lstm, dim3(32), dim3(256), 0, stream, tsp, Wg, bd1, bd2, P,
                           out1, out2, cst, cx, cnt, c * CH_);
    }
    hipLaunchKernelGGL(k4a_alpha, dim3(64), dim3(512), 0, stream, out1, wa, alp);
    hipLaunchKernelGGL(k4b_ctx, dim3(64), dim3(512), 0, stream, out2, Wbb, embB, alp, ctx);
    hipLaunchKernelGGL(k4c_out, dim3(64), dim3(128), 0, stream, ctx, Wout, out);
}

// Round 5
// 1735355.273 us; speedup vs baseline: 4.3574x; 4.3574x over previous
//
#include <hip/hip_runtime.h>

typedef __attribute__((ext_vector_type(8))) short short8;
typedef __attribute__((ext_vector_type(4))) float f32x4;
typedef __attribute__((ext_vector_type(4))) unsigned int u32x4;

#define B_   64
#define S_   512
#define V_   1400
#define VP_  1408
#define H_   256
#define G4_  1024
#define NC_  128
#define CH_  64    // time-chunk length (8 chunks of 64 steps)

__device__ __forceinline__ unsigned short f2bf(float f) {
    unsigned u = __builtin_bit_cast(unsigned, f);
    u += 0x7FFFu + ((u >> 16) & 1u);
    return (unsigned short)(u >> 16);
}
__device__ __forceinline__ float bf2f(unsigned short h) {
    unsigned u = ((unsigned)h) << 16;
    return __builtin_bit_cast(float, u);
}
__device__ __forceinline__ float fsig(float x) {
    x = fminf(fmaxf(x, -40.f), 40.f);
    float e = __builtin_amdgcn_exp2f(x * -1.44269504f);
    return __builtin_amdgcn_rcpf(1.0f + e);
}
__device__ __forceinline__ float ftanh(float x) {
    x = fminf(fmaxf(x, -40.f), 40.f);
    float e = __builtin_amdgcn_exp2f(x * 2.88539008f);
    return 1.0f - 2.0f * __builtin_amdgcn_rcpf(e + 1.0f);
}

// ---- IC-coherent (cross-XCD) primitives — proven fallback path ----
__device__ __forceinline__ short8 gload16_sc1(const unsigned short* p) {
    short8 r;
    asm volatile("global_load_dwordx4 %0, %1, off sc1"
                 : "=&v"(r) : "v"((unsigned long long)p));
    return r;
}
__device__ __forceinline__ void gstore_short_sc1(unsigned short* p, unsigned v) {
    asm volatile("global_store_short %0, %1, off sc1"
                 :: "v"((unsigned long long)p), "v"(v));
}
// ---- L2-local (same-XCD) primitives — fast path (data path PROVEN round-4:
// plain write-through store -> vmcnt ack -> sc0 load returns correct peer data
// within one XCD; 512 steps incl. parity-2 cx reuse ran bit-correct) ----
__device__ __forceinline__ short8 gload16_sc0(const unsigned short* p) {
    short8 r;
    asm volatile("global_load_dwordx4 %0, %1, off sc0"
                 : "=&v"(r) : "v"((unsigned long long)p));
    return r;
}
__device__ __forceinline__ void gstore_short_plain(unsigned short* p, unsigned v) {
    asm volatile("global_store_short %0, %1, off"
                 :: "v"((unsigned long long)p), "v"(v));
}
__device__ __forceinline__ void gstore_dword_plain(unsigned int* p, unsigned v) {
    asm volatile("global_store_dword %0, %1, off"
                 :: "v"((unsigned long long)p), "v"(v));
}
// 16-flag poll: 4x dwordx4 sc0 + single vmcnt drain. Early-clobber outputs so
// they never alias the 4 address pairs inside the spin loop.
__device__ __forceinline__ void gpoll16_sc0(const unsigned int* p,
                                            u32x4& f0, u32x4& f1, u32x4& f2, u32x4& f3) {
    asm volatile("global_load_dwordx4 %0, %4, off sc0\n\t"
                 "global_load_dwordx4 %1, %5, off sc0\n\t"
                 "global_load_dwordx4 %2, %6, off sc0\n\t"
                 "global_load_dwordx4 %3, %7, off sc0\n\t"
                 "s_waitcnt vmcnt(0)"
                 : "=&v"(f0), "=&v"(f1), "=&v"(f2), "=&v"(f3)
                 : "v"((unsigned long long)p),        "v"((unsigned long long)(p + 4)),
                   "v"((unsigned long long)(p + 8)),  "v"((unsigned long long)(p + 12)));
}

// cnt zone layout (ints): fallback step counters (chunk*8+grp)*64  [0,4096)
//                         rdy[chunk] at 4096+chunk*64              [4096,4608)
//                         xpub[32]   at 4608                       [4608,4640)
//                         flags      at 5120+(chunk*8+grp)*16      [5120,6144)
#define CNT_ZONE_ 6144

// ---------------------------------------------------------------- K0: prep
__global__ void k0_prep(const float* __restrict__ emb,
                        const float* __restrict__ Wa1, const float* __restrict__ Wa2,
                        const float* __restrict__ Wd1, const float* __restrict__ Wd2,
                        const float* __restrict__ U1,  const float* __restrict__ U2,
                        const float* __restrict__ ba1, const float* __restrict__ bu1,
                        const float* __restrict__ ba2, const float* __restrict__ bu2,
                        const float* __restrict__ Wb,
                        unsigned short* __restrict__ embT, unsigned short* __restrict__ Wg,
                        unsigned short* __restrict__ Wd,   unsigned short* __restrict__ Ub,
                        unsigned short* __restrict__ Wbb,  float* __restrict__ bg,
                        unsigned int* __restrict__ cnt) {
    int tid = blockIdx.x * blockDim.x + threadIdx.x;
    int np = gridDim.x * blockDim.x;
    for (int i = tid; i < 256 * VP_; i += np) {
        int n = i / VP_, k = i - n * VP_;
        embT[i] = (k < V_) ? f2bf(emb[k * H_ + n]) : (unsigned short)0;
    }
    for (int i = tid; i < G4_ * H_; i += np) {
        Wg[i] = f2bf(Wa1[i]); Wg[G4_ * H_ + i] = f2bf(Wa2[i]);
        Ub[i] = f2bf(U1[i]);  Ub[G4_ * H_ + i] = f2bf(U2[i]);
    }
    for (int i = tid; i < H_ * H_; i += np) {
        Wd[i] = f2bf(Wd1[i]); Wd[H_ * H_ + i] = f2bf(Wd2[i]); Wbb[i] = f2bf(Wb[i]);
    }
    for (int i = tid; i < G4_; i += np) {
        bg[i] = ba1[i] + bu1[i]; bg[G4_ + i] = ba2[i] + bu2[i];
    }
    for (int i = tid; i < CNT_ZONE_; i += np) cnt[i] = 0;   // sync zone (re-zeroed every run)
}

// ---------------------------------------------------------------- K1: embedded = inputs @ emb
__global__ __launch_bounds__(512, 2) void k1_embed(const float* __restrict__ inputs,
                                                   const unsigned short* __restrict__ embT,
                                                   unsigned short* __restrict__ embB) {
    const int tid = threadIdx.x;
    const int w = tid >> 6, ln = tid & 63, q = ln >> 4, l16 = ln & 15;
    const int mt = w >> 2, ng = (w & 3) * 4;
    const int Rbase = blockIdx.x * 32 + mt * 16;
    const float* arow = inputs + (long)(Rbase + l16) * V_;

    f32x4 acc[4];
    #pragma unroll
    for (int i = 0; i < 4; ++i) acc[i] = (f32x4){0.f, 0.f, 0.f, 0.f};

    for (int kt = 0; kt < 44; ++kt) {
        int k0 = kt * 32 + q * 8;
        short8 af;
        if (kt == 43 && q == 3) {
            #pragma unroll
            for (int j = 0; j < 8; ++j) af[j] = 0;
        } else {
            f32x4 x0 = *(const f32x4*)(arow + k0);
            f32x4 x1 = *(const f32x4*)(arow + k0 + 4);
            #pragma unroll
            for (int j = 0; j < 4; ++j) { af[j] = (short)f2bf(x0[j]); af[4 + j] = (short)f2bf(x1[j]); }
        }
        #pragma unroll
        for (int i = 0; i < 4; ++i) {
            short8 bf = *(const short8*)(embT + (long)((ng + i) * 16 + l16) * VP_ + k0);
            acc[i] = __builtin_amdgcn_mfma_f32_16x16x32_bf16(af, bf, acc[i], 0, 0, 0);
        }
    }
    #pragma unroll
    for (int i = 0; i < 4; ++i) {
        int col = (ng + i) * 16 + l16;
        #pragma unroll
        for (int j = 0; j < 4; ++j) {
            int R = Rbase + 4 * q + j;
            embB[(long)R * H_ + col] = f2bf(acc[i][j]);
        }
    }
}

// ---------------------------------------------------------------- K2: P chunk = embedded @ [U1;U2]^T + bg
__global__ __launch_bounds__(512, 2) void k2_pre(const unsigned short* __restrict__ embB,
                                                 const unsigned short* __restrict__ Ub,
                                                 const float* __restrict__ bg,
                                                 float* __restrict__ P, int t0) {
    const int tid = threadIdx.x;
    const int w = tid >> 6, ln = tid & 63, q = ln >> 4, l16 = ln & 15;
    const int rbase = blockIdx.x * 32;  // local row' in chunk, 0..4095

    short8 af[2][8];
    #pragma unroll
    for (int mt = 0; mt < 2; ++mt)
        #pragma unroll
        for (int kt = 0; kt < 8; ++kt) {
            int rp = rbase + mt * 16 + l16;
            int rg = t0 * 64 + rp;
            int b = rg & 63, s = rg >> 6;
            af[mt][kt] = *(const short8*)(embB + ((long)b * S_ + s) * H_ + kt * 32 + q * 8);
        }

    for (int i = 0; i < 16; ++i) {
        int nt2 = w * 16 + i;          // global gate-col tile 0..127
        int l = nt2 >> 6;
        int gcol = (nt2 & 63) * 16 + l16;   // col within lstm, 0..1023
        float bias = bg[nt2 * 16 + l16];
        short8 bf[8];
        #pragma unroll
        for (int kt = 0; kt < 8; ++kt)
            bf[kt] = *(const short8*)(Ub + (long)(nt2 * 16 + l16) * H_ + kt * 32 + q * 8);
        #pragma unroll
        for (int mt = 0; mt < 2; ++mt) {
            f32x4 acc = (f32x4){bias, bias, bias, bias};
            #pragma unroll
            for (int kt = 0; kt < 8; ++kt)
                acc = __builtin_amdgcn_mfma_f32_16x16x32_bf16(af[mt][kt], bf[kt], acc, 0, 0, 0);
            int rp0 = rbase + mt * 16;
            float* dst = P + ((long)l * (CH_ * 64) + rp0 + 4 * q) * G4_ + gcol;
            #pragma unroll
            for (int j = 0; j < 4; ++j) dst[(long)j * G4_] = acc[j];
        }
    }
}

// ---------------------------------------------------------------- K3: time-LSTM chunk (64 steps)
// Round-10: fast path sync rebuilt on PLAIN-STORE flags (no atomics in hot loop).
//   Round-4 forensics: fast path ran; plain-store->sc0-load data exchange in the
//   shared XCD L2 was bit-correct; but the global_atomic_add counter was
//   INVISIBLE to sc0 polls (atomic executes at/through the device coherent
//   point; the XCD L2 served a stale clean copy) -> every poll burned its full
//   bound -> 7.5s. Fix: per-wave flag dwords in one 64B line per (chunk,group),
//   posted with the SAME plain-store primitive the data path proved, polled
//   with 4x dwordx4 sc0 + one vmcnt drain. Flags monotonic (t+1); entering
//   step t+2 requires all flags >= t+1, which post-dates every read of cx(t),
//   so the parity-2 c-exchange stays safe. P prefetch at loop bottom so its
//   latency hides under the poll. Poll bound 2^15 (broken protocol => ~2s run,
//   diagnosable, not a hang). Fallback: proven IC-scope protocol, untouched.
__global__ __launch_bounds__(256, 1) void k3_lstm(const float* __restrict__ ts,
                                                  const unsigned short* __restrict__ W, // Wg || Wd
                                                  const float* __restrict__ bd1,
                                                  const float* __restrict__ bd2,
                                                  const float* __restrict__ P,
                                                  unsigned short* __restrict__ out1,
                                                  unsigned short* __restrict__ out2,
                                                  float* __restrict__ cst,
                                                  unsigned short* __restrict__ cx,
                                                  unsigned int* __restrict__ cnt,
                                                  int t0) {
    __shared__ float ts_lds[16][CH_];

    const int tid = threadIdx.x;
    const int w = tid >> 6, ln = tid & 63, q = ln >> 4, l16 = ln & 15;
    const int bid = blockIdx.x;
    const int chunk = t0 >> 6;

    // -------- XCD discovery (IC-scope handshake, once per launch) ------------
    const int myx = (int)__builtin_amdgcn_s_getreg(63508);  // HW_REG_XCC_ID
    unsigned int* rdy  = cnt + 4096 + chunk * 64;
    int*          xpub = (int*)(cnt + 4608);
    if (tid == 0) {
        __hip_atomic_store(&xpub[bid], myx, __ATOMIC_RELAXED, __HIP_MEMORY_SCOPE_AGENT);
        __hip_atomic_fetch_add(rdy, 1u, __ATOMIC_RELEASE, __HIP_MEMORY_SCOPE_AGENT);
    }
    unsigned hs_it = 0;
    while (__hip_atomic_load(rdy, __ATOMIC_ACQUIRE, __HIP_MEMORY_SCOPE_AGENT) < 32u
           && ++hs_it < (1u << 20))
        __builtin_amdgcn_s_sleep(2);
    int xv[32];
    #pragma unroll
    for (int i = 0; i < 32; ++i)
        xv[i] = __hip_atomic_load(&xpub[i], __ATOMIC_RELAXED, __HIP_MEMORY_SCOPE_AGENT);
    unsigned okA = 1, inr = 1, mask = 0;
    #pragma unroll
    for (int g = 0; g < 8; ++g)
        okA &= (unsigned)((xv[g] == xv[g + 8]) & (xv[g] == xv[g + 16]) & (xv[g] == xv[g + 24]));
    #pragma unroll
    for (int i = 0; i < 32; ++i) {
        inr &= (unsigned)((unsigned)xv[i] < 8u);
        mask |= 1u << ((unsigned)xv[i] & 31u);
    }
    const bool fast = okA && inr && (mask == 0xFFu) && (hs_it < (1u << 20));

    // -------- role decode (identical for both paths) -------------------------
    const int grp = bid & 7, cg = bid >> 3;    // mapping A: {g,g+8,g+16,g+24} co-XCD
    const int l = grp >> 2, m = grp & 3, b0 = m * 16;
    const int hc0 = cg * 64 + w * 16;
    const int mycol = hc0 + l16;
    unsigned int* cell  = cnt + (chunk * 8 + grp) * 64;        // fallback counter
    unsigned int* fcell = cnt + 5120 + (chunk * 8 + grp) * 16; // 16 flag dwords (64B)
    unsigned int* myflag = fcell + (cg * 4 + w);
    unsigned short* outp = l ? out2 : out1;
    const float bdv = (l ? bd2 : bd1)[mycol];

    for (int i = tid; i < 16 * CH_; i += 256) {
        int r = i >> 6, cc = i & (CH_ - 1);
        ts_lds[r][cc] = ts[(b0 + r) * S_ + t0 + cc];
    }

    // -------- register/AGPR-resident weights (loaded once per launch) --------
    short8 wg[4][8];
    short8 wd[8];
    #pragma unroll
    for (int g = 0; g < 4; ++g)
        #pragma unroll
        for (int kt = 0; kt < 8; ++kt)
            wg[g][kt] = *(const short8*)(W + ((long)(l * G4_ + g * H_ + mycol)) * H_ + kt * 32 + q * 8);
    #pragma unroll
    for (int kt = 0; kt < 8; ++kt)
        wd[kt] = *(const short8*)(W + (long)2 * G4_ * H_ + ((long)(l * H_ + mycol)) * H_ + kt * 32 + q * 8);

    float cf[4];
    if (t0 == 0) {
        cf[0] = cf[1] = cf[2] = cf[3] = 0.f;
    } else {
        #pragma unroll
        for (int j = 0; j < 4; ++j)
            cf[j] = cst[(long)(l * 4 + m) * 4096 + (4 * q + j) * 256 + mycol];
    }
    __syncthreads();   // ts_lds ready

    const float* Pbase = P + ((long)l * (CH_ * 64) + b0) * G4_;

    if (fast) {
        // ================= FAST: same-XCD, L2-scope protocol =================
        float pv[4][4];
        #pragma unroll
        for (int g = 0; g < 4; ++g)
            #pragma unroll
            for (int j = 0; j < 4; ++j)
                pv[g][j] = Pbase[((long)(4 * q + j)) * G4_ + g * H_ + mycol];
        asm volatile("" ::: "memory");

        #pragma unroll 1
        for (int t = 0; t < CH_; ++t) {
            const int gt = t0 + t;

            if (t) {   // wait: all 16 waves of this group posted step t-1 (bounded)
                unsigned it = 0;
                const unsigned tt = (unsigned)t;
                for (;;) {
                    u32x4 f0, f1, f2, f3;
                    gpoll16_sc0(fcell, f0, f1, f2, f3);
                    unsigned ok = 1;
                    #pragma unroll
                    for (int i = 0; i < 4; ++i)
                        ok &= (unsigned)(f0[i] >= tt) & (unsigned)(f1[i] >= tt) &
                              (unsigned)(f2[i] >= tt) & (unsigned)(f3[i] >= tt);
                    if (ok || ++it >= (1u << 15)) break;
                }
            }
            __builtin_amdgcn_sched_barrier(0);

            short8 ha[8], ca[8];
            if (gt == 0) {
                #pragma unroll
                for (int kt = 0; kt < 8; ++kt) {
                    #pragma unroll
                    for (int j = 0; j < 8; ++j) { ha[kt][j] = 0; ca[kt][j] = 0; }
                }
            } else {
                const unsigned short* crow = cx + ((long)(((gt - 1) & 1) * 8 + grp)) * 4096 + l16 * 256 + q * 8;
                const unsigned short* hrow = outp + ((long)(b0 + l16) * S_ + (gt - 1)) * H_ + q * 8;
                #pragma unroll
                for (int kt = 0; kt < 8; ++kt) ca[kt] = gload16_sc0(crow + kt * 32);
                #pragma unroll
                for (int kt = 0; kt < 8; ++kt) ha[kt] = gload16_sc0(hrow + kt * 32);
            }
            asm volatile("s_waitcnt vmcnt(8)" ::: "memory");   // ca complete
            __builtin_amdgcn_sched_barrier(0);

            f32x4 dacc = (f32x4){bdv, bdv, bdv, bdv};
            #pragma unroll
            for (int kt = 0; kt < 8; ++kt)
                dacc = __builtin_amdgcn_mfma_f32_16x16x32_bf16(ca[kt], wd[kt], dacc, 0, 0, 0);

            asm volatile("s_waitcnt vmcnt(0)" ::: "memory");   // ha complete
            __builtin_amdgcn_sched_barrier(0);

            f32x4 gacc[4];
            #pragma unroll
            for (int g = 0; g < 4; ++g) {
                gacc[g] = (f32x4){pv[g][0], pv[g][1], pv[g][2], pv[g][3]};
                #pragma unroll
                for (int kt = 0; kt < 8; ++kt)
                    gacc[g] = __builtin_amdgcn_mfma_f32_16x16x32_bf16(ha[kt], wg[g][kt], gacc[g], 0, 0, 0);
            }

            #pragma unroll
            for (int j = 0; j < 4; ++j) {
                int r = 4 * q + j;
                float tv = ts_lds[r][t];
                float cs1 = ftanh(dacc[j]);
                float cadj = cf[j] + cs1 * (tv - 1.0f);
                float fg = fsig(gacc[0][j]), ig = fsig(gacc[1][j]);
                float og = fsig(gacc[2][j]), ct = fsig(gacc[3][j]);
                float cn = fg * cadj + ig * ct;
                float hn = og * ftanh(cn);
                cf[j] = cn;
                gstore_short_plain(outp + ((long)(b0 + r) * S_ + gt) * H_ + mycol, (unsigned)f2bf(hn));
                gstore_short_plain(cx + ((long)((gt & 1) * 8 + grp)) * 4096 + r * 256 + mycol, (unsigned)f2bf(cn));
            }
            asm volatile("s_waitcnt vmcnt(0)" ::: "memory");   // data ack'd at L2
            if (ln == 0) gstore_dword_plain(myflag, (unsigned)(t + 1));  // post

            // prefetch P(t+1): lands during next poll (clamped at the tail)
            {
                int tn = (t + 1 < CH_) ? t + 1 : t;
                asm volatile("" ::: "memory");
                #pragma unroll
                for (int g = 0; g < 4; ++g)
                    #pragma unroll
                    for (int j = 0; j < 4; ++j)
                        pv[g][j] = Pbase[((long)tn * 64 + 4 * q + j) * G4_ + g * H_ + mycol];
                asm volatile("" ::: "memory");
            }
        }
    } else {
        // ============ FALLBACK: proven IC-scope protocol (round-7) ============
        #pragma unroll 1
        for (int t = 0; t < CH_; ++t) {
            const int gt = t0 + t;

            float pv[4][4];
            #pragma unroll
            for (int g = 0; g < 4; ++g)
                #pragma unroll
                for (int j = 0; j < 4; ++j)
                    pv[g][j] = Pbase[((long)t * 64 + 4 * q + j) * G4_ + g * H_ + mycol];
            asm volatile("" ::: "memory");

            {
                unsigned tgt = 4u * (unsigned)t, it = 0;
                while (__hip_atomic_load(cell, __ATOMIC_RELAXED, __HIP_MEMORY_SCOPE_AGENT) < tgt
                       && ++it < (1u << 18))
                    __builtin_amdgcn_s_sleep(1);
            }

            short8 ha[8], ca[8];
            if (gt == 0) {
                #pragma unroll
                for (int kt = 0; kt < 8; ++kt) {
                    #pragma unroll
                    for (int j = 0; j < 8; ++j) { ha[kt][j] = 0; ca[kt][j] = 0; }
                }
            } else {
                const unsigned short* crow = cx + ((long)(((gt - 1) & 1) * 8 + grp)) * 4096 + l16 * 256 + q * 8;
                const unsigned short* hrow = outp + ((long)(b0 + l16) * S_ + (gt - 1)) * H_ + q * 8;
                #pragma unroll
                for (int kt = 0; kt < 8; ++kt) ca[kt] = gload16_sc1(crow + kt * 32);
                #pragma unroll
                for (int kt = 0; kt < 8; ++kt) ha[kt] = gload16_sc1(hrow + kt * 32);
            }
            asm volatile("s_waitcnt vmcnt(8)" ::: "memory");
            __builtin_amdgcn_sched_barrier(0);

            f32x4 dacc = (f32x4){bdv, bdv, bdv, bdv};
            #pragma unroll
            for (int kt = 0; kt < 8; ++kt)
                dacc = __builtin_amdgcn_mfma_f32_16x16x32_bf16(ca[kt], wd[kt], dacc, 0, 0, 0);

            asm volatile("s_waitcnt vmcnt(0)" ::: "memory");
            __builtin_amdgcn_sched_barrier(0);

            f32x4 gacc[4];
            #pragma unroll
            for (int g = 0; g < 4; ++g) {
                gacc[g] = (f32x4){pv[g][0], pv[g][1], pv[g][2], pv[g][3]};
                #pragma unroll
                for (int kt = 0; kt < 8; ++kt)
                    gacc[g] = __builtin_amdgcn_mfma_f32_16x16x32_bf16(ha[kt], wg[g][kt], gacc[g], 0, 0, 0);
            }

            #pragma unroll
            for (int j = 0; j < 4; ++j) {
                int r = 4 * q + j;
                float tv = ts_lds[r][t];
                float cs1 = ftanh(dacc[j]);
                float cadj = cf[j] + cs1 * (tv - 1.0f);
                float fg = fsig(gacc[0][j]), ig = fsig(gacc[1][j]);
                float og = fsig(gacc[2][j]), ct = fsig(gacc[3][j]);
                float cn = fg * cadj + ig * ct;
                float hn = og * ftanh(cn);
                cf[j] = cn;
                gstore_short_sc1(outp + ((long)(b0 + r) * S_ + gt) * H_ + mycol, (unsigned)f2bf(hn));
                gstore_short_sc1(cx + ((long)((gt & 1) * 8 + grp)) * 4096 + r * 256 + mycol, (unsigned)f2bf(cn));
            }
            asm volatile("s_waitcnt vmcnt(0)" ::: "memory");
            __syncthreads();
            if (tid == 0) atomicAdd(cell, 1u);
        }
    }

    // persist fp32 c for next chunk
    #pragma unroll
    for (int j = 0; j < 4; ++j)
        cst[(long)(l * 4 + m) * 4096 + (4 * q + j) * 256 + mycol] = cf[j];
}

// ---------------------------------------------------------------- K4a: scores + softmax -> alpha
__global__ __launch_bounds__(512) void k4a_alpha(const unsigned short* __restrict__ out1,
                                                 const float* __restrict__ wa,
                                                 float* __restrict__ alpha) {
    __shared__ float sc[512];
    __shared__ float red[512];
    const int b = blockIdx.x, tid = threadIdx.x;
    const int w = tid >> 6, ln = tid & 63;
    f32x4 wv = *(const f32x4*)(wa + ln * 4);
    for (int i = 0; i < 64; ++i) {
        int s = w * 64 + i;
        const unsigned short* row = out1 + ((long)b * S_ + s) * H_ + ln * 4;
        float d = bf2f(row[0]) * wv[0] + bf2f(row[1]) * wv[1] +
                  bf2f(row[2]) * wv[2] + bf2f(row[3]) * wv[3];
        #pragma unroll
        for (int off = 32; off; off >>= 1) d += __shfl_xor(d, off);
        if (ln == 0) sc[s] = d;
    }
    __syncthreads();
    float v = sc[tid];
    red[tid] = v;
    for (int st = 256; st; st >>= 1) {
        __syncthreads();
        if (tid < st) red[tid] = fmaxf(red[tid], red[tid + st]);
    }
    __syncthreads();
    float M = red[0];
    __syncthreads();
    float e = __builtin_amdgcn_exp2f((v - M) * 1.44269504f);
    red[tid] = e;
    for (int st = 256; st; st >>= 1) {
        __syncthreads();
        if (tid < st) red[tid] += red[tid + st];
    }
    __syncthreads();
    alpha[b * S_ + tid] = e * __builtin_amdgcn_rcpf(red[0]);
}

// ---------------------------------------------------------------- K4b: Beta=tanh(out2@Wb^T); ctx = sum_s emb*Beta*alpha
__global__ __launch_bounds__(512, 2) void k4b_ctx(const unsigned short* __restrict__ out2,
                                                  const unsigned short* __restrict__ Wbb,
                                                  const unsigned short* __restrict__ embB,
                                                  const float* __restrict__ alpha,
                                                  float* __restrict__ ctx) {
    __shared__ float cbuf[32][256];
    const int b = blockIdx.x, tid = threadIdx.x;
    const int w = tid >> 6, ln = tid & 63, q = ln >> 4, l16 = ln & 15;

    float cp[16];
    #pragma unroll
    for (int nt = 0; nt < 16; ++nt) cp[nt] = 0.f;

    for (int i = 0; i < 4; ++i) {
        int mt = w * 4 + i;
        short8 af[8];
        #pragma unroll
        for (int kt = 0; kt < 8; ++kt)
            af[kt] = *(const short8*)(out2 + ((long)b * S_ + mt * 16 + l16) * H_ + kt * 32 + q * 8);
        float al[4];
        #pragma unroll
        for (int j = 0; j < 4; ++j) al[j] = alpha[b * S_ + mt * 16 + 4 * q + j];
        for (int nt = 0; nt < 16; ++nt) {
            f32x4 acc = (f32x4){0.f, 0.f, 0.f, 0.f};
            #pragma unroll
            for (int kt = 0; kt < 8; ++kt) {
                short8 bf = *(const short8*)(Wbb + (long)(nt * 16 + l16) * H_ + kt * 32 + q * 8);
                acc = __builtin_amdgcn_mfma_f32_16x16x32_bf16(af[kt], bf, acc, 0, 0, 0);
            }
            #pragma unroll
            for (int j = 0; j < 4; ++j) {
                int s = mt * 16 + 4 * q + j;
                float beta = ftanh(acc[j]);
                float ev = bf2f(embB[((long)b * S_ + s) * H_ + nt * 16 + l16]);
                cp[nt] += beta * al[j] * ev;
            }
        }
    }
    #pragma unroll
    for (int nt = 0; nt < 16; ++nt) cbuf[w * 4 + q][nt * 16 + l16] = cp[nt];
    __syncthreads();
    if (tid < 256) {
        float sum = 0.f;
        for (int i = 0; i < 32; ++i) sum += cbuf[i][tid];
        ctx[b * H_ + tid] = sum;
    }
}

// ---------------------------------------------------------------- K4c: out = ctx @ W_out^T
__global__ void k4c_out(const float* __restrict__ ctx, const float* __restrict__ Wout,
                        float* __restrict__ out) {
    int b = blockIdx.x, n = threadIdx.x;
    const f32x4* cr = (const f32x4*)(ctx + b * H_);
    const f32x4* wr = (const f32x4*)(Wout + n * H_);
    float acc = 0.f;
    #pragma unroll 8
    for (int i = 0; i < 64; ++i) {
        f32x4 c = cr[i], ww = wr[i];
        acc += c[0] * ww[0] + c[1] * ww[1] + c[2] * ww[2] + c[3] * ww[3];
    }
    out[b * NC_ + n] = acc;
}

// ---------------------------------------------------------------- launch
extern "C" void kernel_launch(void* const* d_in, const int* in_sizes, int n_in,
                              void* d_out, int out_size, void* d_ws, size_t ws_size,
                              hipStream_t stream) {
    (void)in_sizes; (void)n_in; (void)out_size; (void)ws_size;
    const float* inputs = (const float*)d_in[0];
    const float* tsp    = (const float*)d_in[1];
    const float* emb    = (const float*)d_in[2];
    const float* Wa1 = (const float*)d_in[3];  const float* ba1 = (const float*)d_in[4];
    const float* U1  = (const float*)d_in[5];  const float* bu1 = (const float*)d_in[6];
    const float* Wd1 = (const float*)d_in[7];  const float* bd1 = (const float*)d_in[8];
    const float* Wa2 = (const float*)d_in[9];  const float* ba2 = (const float*)d_in[10];
    const float* U2  = (const float*)d_in[11]; const float* bu2 = (const float*)d_in[12];
    const float* Wd2 = (const float*)d_in[13]; const float* bd2 = (const float*)d_in[14];
    const float* wa  = (const float*)d_in[15];
    const float* Wb  = (const float*)d_in[16];
    const float* Wout = (const float*)d_in[17];
    float* out = (float*)d_out;

    // Workspace map (round-10: cnt zone 24,576B — adds the 64B flag lines).
    char* ws = (char*)d_ws;
    unsigned short* embT = (unsigned short*)(ws + 0);            //    720,896
    unsigned short* Wg   = (unsigned short*)(ws + 720896);       //  1,048,576 (Wd must follow)
    unsigned short* Wd   = (unsigned short*)(ws + 1769472);      //    262,144
    unsigned short* Ub   = (unsigned short*)(ws + 2031616);      //  1,048,576
    unsigned short* Wbb  = (unsigned short*)(ws + 3080192);      //    131,072
    float*          bgp  = (float*)(ws + 3211264);               //      8,192
    unsigned short* embB = (unsigned short*)(ws + 3219456);      // 16,777,216
    float*          P    = (float*)(ws + 19996672);              // 33,554,432 (64-step chunk)
    unsigned short* out1 = (unsigned short*)(ws + 53551104);     // 16,777,216
    unsigned short* out2 = (unsigned short*)(ws + 70328320);     // 16,777,216
    unsigned short* cx   = (unsigned short*)(ws + 87105536);     //    131,072 ([2 parity][8 grp][16][256] bf16)
    float*          cst  = (float*)(ws + 87236608);              //    131,072
    float*          alp  = (float*)(ws + 87367680);              //    131,072
    float*          ctx  = (float*)(ws + 87498752);              //     65,536
    unsigned int*   cnt  = (unsigned int*)(ws + 87564288);       //     24,576
    // total: 87,588,864 bytes (~83.5 MiB)

    hipLaunchKernelGGL(k0_prep, dim3(256), dim3(256), 0, stream,
                       emb, Wa1, Wa2, Wd1, Wd2, U1, U2, ba1, bu1, ba2, bu2, Wb,
                       embT, Wg, Wd, Ub, Wbb, bgp, cnt);
    hipLaunchKernelGGL(k1_embed, dim3(1024), dim3(512), 0, stream, inputs, embT, embB);
    for (int c = 0; c < 8; ++c) {
        hipLaunchKernelGGL(k2_pre, dim3(128), dim3(512), 0, stream, embB, Ub, bgp, P, c * CH_);
        hipLaunchKernelGGL(k3_lstm, dim3(32), dim3(256), 0, stream, tsp, Wg, bd1, bd2, P,
                           out1, out2, cst, cx, cnt, c * CH_);
    }
    hipLaunchKernelGGL(k4a_alpha, dim3(64), dim3(512), 0, stream, out1, wa, alp);
    hipLaunchKernelGGL(k4b_ctx, dim3(64), dim3(512), 0, stream, out2, Wbb, embB, alp, ctx);
    hipLaunchKernelGGL(k4c_out, dim3(64), dim3(128), 0, stream, ctx, Wout, out);
}

// Round 6
// 3077.223 us; speedup vs baseline: 2457.2760x; 563.9355x over previous
//
#include <hip/hip_runtime.h>

typedef __attribute__((ext_vector_type(8))) short short8;
typedef __attribute__((ext_vector_type(4))) float f32x4;

#define B_   64
#define S_   512
#define V_   1400
#define VP_  1408
#define H_   256
#define G4_  1024
#define NC_  128
#define CH_  64    // time-chunk length (8 chunks of 64 steps)

__device__ __forceinline__ unsigned short f2bf(float f) {
    unsigned u = __builtin_bit_cast(unsigned, f);
    u += 0x7FFFu + ((u >> 16) & 1u);
    return (unsigned short)(u >> 16);
}
__device__ __forceinline__ float bf2f(unsigned short h) {
    unsigned u = ((unsigned)h) << 16;
    return __builtin_bit_cast(float, u);
}
__device__ __forceinline__ float fsig(float x) {
    x = fminf(fmaxf(x, -40.f), 40.f);
    float e = __builtin_amdgcn_exp2f(x * -1.44269504f);
    return __builtin_amdgcn_rcpf(1.0f + e);
}
__device__ __forceinline__ float ftanh(float x) {
    x = fminf(fmaxf(x, -40.f), 40.f);
    float e = __builtin_amdgcn_exp2f(x * 2.88539008f);
    return 1.0f - 2.0f * __builtin_amdgcn_rcpf(e + 1.0f);
}

// ---- IC-coherent (cross-XCD) primitives — proven fallback path ----
__device__ __forceinline__ short8 gload16_sc1(const unsigned short* p) {
    short8 r;
    asm volatile("global_load_dwordx4 %0, %1, off sc1"
                 : "=&v"(r) : "v"((unsigned long long)p));
    return r;
}
__device__ __forceinline__ void gstore_short_sc1(unsigned short* p, unsigned v) {
    asm volatile("global_store_short %0, %1, off sc1"
                 :: "v"((unsigned long long)p), "v"(v));
}
// ---- L2-local (same-XCD) primitives — fast path.
// Round-5 forensics: sc0 loads do NOT bypass L1 on gfx950 (spin-polled line
// stays stale in the poller's L1 forever). Data gathers only worked because
// per-step traffic evicted their lines + timeout delays. Fix: (a) poll/post
// via ATOMICS (TCC-executed, L1-free by construction); (b) acquire fence
// (buffer_inv) after a successful poll so gathers can never hit stale L1.
__device__ __forceinline__ short8 gload16_sc0(const unsigned short* p) {
    short8 r;
    asm volatile("global_load_dwordx4 %0, %1, off sc0"
                 : "=&v"(r) : "v"((unsigned long long)p));
    return r;
}
__device__ __forceinline__ void gstore_short_plain(unsigned short* p, unsigned v) {
    asm volatile("global_store_short %0, %1, off"
                 :: "v"((unsigned long long)p), "v"(v));
}

// cnt zone layout (ints): step counters (chunk*8+grp)*64  [0,4096)
//                         rdy[chunk] at 4096+chunk*64     [4096,4608)
//                         xpub[32]   at 4608              [4608,4640)
#define CNT_ZONE_ 6144

// ---------------------------------------------------------------- K0: prep
__global__ void k0_prep(const float* __restrict__ emb,
                        const float* __restrict__ Wa1, const float* __restrict__ Wa2,
                        const float* __restrict__ Wd1, const float* __restrict__ Wd2,
                        const float* __restrict__ U1,  const float* __restrict__ U2,
                        const float* __restrict__ ba1, const float* __restrict__ bu1,
                        const float* __restrict__ ba2, const float* __restrict__ bu2,
                        const float* __restrict__ Wb,
                        unsigned short* __restrict__ embT, unsigned short* __restrict__ Wg,
                        unsigned short* __restrict__ Wd,   unsigned short* __restrict__ Ub,
                        unsigned short* __restrict__ Wbb,  float* __restrict__ bg,
                        unsigned int* __restrict__ cnt) {
    int tid = blockIdx.x * blockDim.x + threadIdx.x;
    int np = gridDim.x * blockDim.x;
    for (int i = tid; i < 256 * VP_; i += np) {
        int n = i / VP_, k = i - n * VP_;
        embT[i] = (k < V_) ? f2bf(emb[k * H_ + n]) : (unsigned short)0;
    }
    for (int i = tid; i < G4_ * H_; i += np) {
        Wg[i] = f2bf(Wa1[i]); Wg[G4_ * H_ + i] = f2bf(Wa2[i]);
        Ub[i] = f2bf(U1[i]);  Ub[G4_ * H_ + i] = f2bf(U2[i]);
    }
    for (int i = tid; i < H_ * H_; i += np) {
        Wd[i] = f2bf(Wd1[i]); Wd[H_ * H_ + i] = f2bf(Wd2[i]); Wbb[i] = f2bf(Wb[i]);
    }
    for (int i = tid; i < G4_; i += np) {
        bg[i] = ba1[i] + bu1[i]; bg[G4_ + i] = ba2[i] + bu2[i];
    }
    for (int i = tid; i < CNT_ZONE_; i += np) cnt[i] = 0;   // sync zone (re-zeroed every run)
}

// ---------------------------------------------------------------- K1: embedded = inputs @ emb
__global__ __launch_bounds__(512, 2) void k1_embed(const float* __restrict__ inputs,
                                                   const unsigned short* __restrict__ embT,
                                                   unsigned short* __restrict__ embB) {
    const int tid = threadIdx.x;
    const int w = tid >> 6, ln = tid & 63, q = ln >> 4, l16 = ln & 15;
    const int mt = w >> 2, ng = (w & 3) * 4;
    const int Rbase = blockIdx.x * 32 + mt * 16;
    const float* arow = inputs + (long)(Rbase + l16) * V_;

    f32x4 acc[4];
    #pragma unroll
    for (int i = 0; i < 4; ++i) acc[i] = (f32x4){0.f, 0.f, 0.f, 0.f};

    for (int kt = 0; kt < 44; ++kt) {
        int k0 = kt * 32 + q * 8;
        short8 af;
        if (kt == 43 && q == 3) {
            #pragma unroll
            for (int j = 0; j < 8; ++j) af[j] = 0;
        } else {
            f32x4 x0 = *(const f32x4*)(arow + k0);
            f32x4 x1 = *(const f32x4*)(arow + k0 + 4);
            #pragma unroll
            for (int j = 0; j < 4; ++j) { af[j] = (short)f2bf(x0[j]); af[4 + j] = (short)f2bf(x1[j]); }
        }
        #pragma unroll
        for (int i = 0; i < 4; ++i) {
            short8 bf = *(const short8*)(embT + (long)((ng + i) * 16 + l16) * VP_ + k0);
            acc[i] = __builtin_amdgcn_mfma_f32_16x16x32_bf16(af, bf, acc[i], 0, 0, 0);
        }
    }
    #pragma unroll
    for (int i = 0; i < 4; ++i) {
        int col = (ng + i) * 16 + l16;
        #pragma unroll
        for (int j = 0; j < 4; ++j) {
            int R = Rbase + 4 * q + j;
            embB[(long)R * H_ + col] = f2bf(acc[i][j]);
        }
    }
}

// ---------------------------------------------------------------- K2: P chunk = embedded @ [U1;U2]^T + bg
__global__ __launch_bounds__(512, 2) void k2_pre(const unsigned short* __restrict__ embB,
                                                 const unsigned short* __restrict__ Ub,
                                                 const float* __restrict__ bg,
                                                 float* __restrict__ P, int t0) {
    const int tid = threadIdx.x;
    const int w = tid >> 6, ln = tid & 63, q = ln >> 4, l16 = ln & 15;
    const int rbase = blockIdx.x * 32;  // local row' in chunk, 0..4095

    short8 af[2][8];
    #pragma unroll
    for (int mt = 0; mt < 2; ++mt)
        #pragma unroll
        for (int kt = 0; kt < 8; ++kt) {
            int rp = rbase + mt * 16 + l16;
            int rg = t0 * 64 + rp;
            int b = rg & 63, s = rg >> 6;
            af[mt][kt] = *(const short8*)(embB + ((long)b * S_ + s) * H_ + kt * 32 + q * 8);
        }

    for (int i = 0; i < 16; ++i) {
        int nt2 = w * 16 + i;          // global gate-col tile 0..127
        int l = nt2 >> 6;
        int gcol = (nt2 & 63) * 16 + l16;   // col within lstm, 0..1023
        float bias = bg[nt2 * 16 + l16];
        short8 bf[8];
        #pragma unroll
        for (int kt = 0; kt < 8; ++kt)
            bf[kt] = *(const short8*)(Ub + (long)(nt2 * 16 + l16) * H_ + kt * 32 + q * 8);
        #pragma unroll
        for (int mt = 0; mt < 2; ++mt) {
            f32x4 acc = (f32x4){bias, bias, bias, bias};
            #pragma unroll
            for (int kt = 0; kt < 8; ++kt)
                acc = __builtin_amdgcn_mfma_f32_16x16x32_bf16(af[mt][kt], bf[kt], acc, 0, 0, 0);
            int rp0 = rbase + mt * 16;
            float* dst = P + ((long)l * (CH_ * 64) + rp0 + 4 * q) * G4_ + gcol;
            #pragma unroll
            for (int j = 0; j < 4; ++j) dst[(long)j * G4_] = acc[j];
        }
    }
}

// ---------------------------------------------------------------- K3: time-LSTM chunk (64 steps)
// Round-11 fast-path sync, per the sc0-L1-staleness finding (round-5):
//   POST: data plain stores -> s_waitcnt vmcnt(0) (data in L2, write-through)
//         -> per-wave fetch_add(cell, 1) at WORKGROUP scope (plain atomic,
//         TCC-executed, L1-free).
//   WAIT: lane0 spins on fetch_add(cell, opaque_zero) — a RETURNING RMW at the
//         same scope/address => same execution point as the posts => coherent.
//         opaque_zero (inline-asm v_mov) blocks InstCombine's idempotent-RMW->
//         atomic-load transform, which would re-emit the L1-stale plain load.
//   Then __builtin_amdgcn_fence(ACQUIRE, "agent") => buffer_inv: gathers can
//         never hit a stale L1 line (rounds 4/5 only dodged this by eviction).
//   Polls bounded (2^14): a broken protocol finishes wrong-but-diagnosable.
//   Fallback: proven round-2 IC-scope protocol, untouched.
__global__ __launch_bounds__(256, 1) void k3_lstm(const float* __restrict__ ts,
                                                  const unsigned short* __restrict__ W, // Wg || Wd
                                                  const float* __restrict__ bd1,
                                                  const float* __restrict__ bd2,
                                                  const float* __restrict__ P,
                                                  unsigned short* __restrict__ out1,
                                                  unsigned short* __restrict__ out2,
                                                  float* __restrict__ cst,
                                                  unsigned short* __restrict__ cx,
                                                  unsigned int* __restrict__ cnt,
                                                  int t0) {
    __shared__ float ts_lds[16][CH_];

    const int tid = threadIdx.x;
    const int w = tid >> 6, ln = tid & 63, q = ln >> 4, l16 = ln & 15;
    const int bid = blockIdx.x;
    const int chunk = t0 >> 6;

    // -------- XCD discovery (IC-scope handshake, once per launch) ------------
    const int myx = (int)__builtin_amdgcn_s_getreg(63508);  // HW_REG_XCC_ID
    unsigned int* rdy  = cnt + 4096 + chunk * 64;
    int*          xpub = (int*)(cnt + 4608);
    if (tid == 0) {
        __hip_atomic_store(&xpub[bid], myx, __ATOMIC_RELAXED, __HIP_MEMORY_SCOPE_AGENT);
        __hip_atomic_fetch_add(rdy, 1u, __ATOMIC_RELEASE, __HIP_MEMORY_SCOPE_AGENT);
    }
    unsigned hs_it = 0;
    while (__hip_atomic_load(rdy, __ATOMIC_ACQUIRE, __HIP_MEMORY_SCOPE_AGENT) < 32u
           && ++hs_it < (1u << 20))
        __builtin_amdgcn_s_sleep(2);
    int xv[32];
    #pragma unroll
    for (int i = 0; i < 32; ++i)
        xv[i] = __hip_atomic_load(&xpub[i], __ATOMIC_RELAXED, __HIP_MEMORY_SCOPE_AGENT);
    unsigned okA = 1, inr = 1, mask = 0;
    #pragma unroll
    for (int g = 0; g < 8; ++g)
        okA &= (unsigned)((xv[g] == xv[g + 8]) & (xv[g] == xv[g + 16]) & (xv[g] == xv[g + 24]));
    #pragma unroll
    for (int i = 0; i < 32; ++i) {
        inr &= (unsigned)((unsigned)xv[i] < 8u);
        mask |= 1u << ((unsigned)xv[i] & 31u);
    }
    const bool fast = okA && inr && (mask == 0xFFu) && (hs_it < (1u << 20));

    // -------- role decode (identical for both paths) -------------------------
    const int grp = bid & 7, cg = bid >> 3;    // mapping A: {g,g+8,g+16,g+24} co-XCD
    const int l = grp >> 2, m = grp & 3, b0 = m * 16;
    const int hc0 = cg * 64 + w * 16;
    const int mycol = hc0 + l16;
    unsigned int* cell = cnt + (chunk * 8 + grp) * 64;   // 256B-spaced, per-chunk
    unsigned short* outp = l ? out2 : out1;
    const float bdv = (l ? bd2 : bd1)[mycol];

    for (int i = tid; i < 16 * CH_; i += 256) {
        int r = i >> 6, cc = i & (CH_ - 1);
        ts_lds[r][cc] = ts[(b0 + r) * S_ + t0 + cc];
    }

    // -------- register/AGPR-resident weights (loaded once per launch) --------
    short8 wg[4][8];
    short8 wd[8];
    #pragma unroll
    for (int g = 0; g < 4; ++g)
        #pragma unroll
        for (int kt = 0; kt < 8; ++kt)
            wg[g][kt] = *(const short8*)(W + ((long)(l * G4_ + g * H_ + mycol)) * H_ + kt * 32 + q * 8);
    #pragma unroll
    for (int kt = 0; kt < 8; ++kt)
        wd[kt] = *(const short8*)(W + (long)2 * G4_ * H_ + ((long)(l * H_ + mycol)) * H_ + kt * 32 + q * 8);

    float cf[4];
    if (t0 == 0) {
        cf[0] = cf[1] = cf[2] = cf[3] = 0.f;
    } else {
        #pragma unroll
        for (int j = 0; j < 4; ++j)
            cf[j] = cst[(long)(l * 4 + m) * 4096 + (4 * q + j) * 256 + mycol];
    }
    __syncthreads();   // ts_lds ready

    const float* Pbase = P + ((long)l * (CH_ * 64) + b0) * G4_;

    if (fast) {
        // ================= FAST: same-XCD, L2-scope protocol =================
        unsigned opaque_zero;
        asm volatile("v_mov_b32 %0, 0" : "=v"(opaque_zero));

        float pv[4][4];
        #pragma unroll
        for (int g = 0; g < 4; ++g)
            #pragma unroll
            for (int j = 0; j < 4; ++j)
                pv[g][j] = Pbase[((long)(4 * q + j)) * G4_ + g * H_ + mycol];
        asm volatile("" ::: "memory");

        #pragma unroll 1
        for (int t = 0; t < CH_; ++t) {
            const int gt = t0 + t;

            if (t) {   // wait: all 16 waves of this group posted step t-1 (bounded)
                const unsigned tgt = 16u * (unsigned)t;
                unsigned it = 0;
                for (;;) {
                    unsigned v = 0;
                    if (ln == 0)
                        v = __hip_atomic_fetch_add(cell, opaque_zero,
                                                   __ATOMIC_RELAXED, __HIP_MEMORY_SCOPE_WORKGROUP);
                    v = __shfl(v, 0);
                    if (v >= tgt || ++it >= (1u << 14)) break;
                }
            }
            // acquire: invalidate L1 so the gathers below read current L2 data
            __builtin_amdgcn_fence(__ATOMIC_ACQUIRE, "agent");
            __builtin_amdgcn_sched_barrier(0);

            short8 ha[8], ca[8];
            if (gt == 0) {
                #pragma unroll
                for (int kt = 0; kt < 8; ++kt) {
                    #pragma unroll
                    for (int j = 0; j < 8; ++j) { ha[kt][j] = 0; ca[kt][j] = 0; }
                }
            } else {
                const unsigned short* crow = cx + ((long)(((gt - 1) & 1) * 8 + grp)) * 4096 + l16 * 256 + q * 8;
                const unsigned short* hrow = outp + ((long)(b0 + l16) * S_ + (gt - 1)) * H_ + q * 8;
                #pragma unroll
                for (int kt = 0; kt < 8; ++kt) ca[kt] = gload16_sc0(crow + kt * 32);
                #pragma unroll
                for (int kt = 0; kt < 8; ++kt) ha[kt] = gload16_sc0(hrow + kt * 32);
            }
            asm volatile("s_waitcnt vmcnt(8)" ::: "memory");   // ca complete
            __builtin_amdgcn_sched_barrier(0);

            f32x4 dacc = (f32x4){bdv, bdv, bdv, bdv};
            #pragma unroll
            for (int kt = 0; kt < 8; ++kt)
                dacc = __builtin_amdgcn_mfma_f32_16x16x32_bf16(ca[kt], wd[kt], dacc, 0, 0, 0);

            asm volatile("s_waitcnt vmcnt(0)" ::: "memory");   // ha complete
            __builtin_amdgcn_sched_barrier(0);

            f32x4 gacc[4];
            #pragma unroll
            for (int g = 0; g < 4; ++g) {
                gacc[g] = (f32x4){pv[g][0], pv[g][1], pv[g][2], pv[g][3]};
                #pragma unroll
                for (int kt = 0; kt < 8; ++kt)
                    gacc[g] = __builtin_amdgcn_mfma_f32_16x16x32_bf16(ha[kt], wg[g][kt], gacc[g], 0, 0, 0);
            }

            #pragma unroll
            for (int j = 0; j < 4; ++j) {
                int r = 4 * q + j;
                float tv = ts_lds[r][t];
                float cs1 = ftanh(dacc[j]);
                float cadj = cf[j] + cs1 * (tv - 1.0f);
                float fg = fsig(gacc[0][j]), ig = fsig(gacc[1][j]);
                float og = fsig(gacc[2][j]), ct = fsig(gacc[3][j]);
                float cn = fg * cadj + ig * ct;
                float hn = og * ftanh(cn);
                cf[j] = cn;
                gstore_short_plain(outp + ((long)(b0 + r) * S_ + gt) * H_ + mycol, (unsigned)f2bf(hn));
                gstore_short_plain(cx + ((long)((gt & 1) * 8 + grp)) * 4096 + r * 256 + mycol, (unsigned)f2bf(cn));
            }
            asm volatile("s_waitcnt vmcnt(0)" ::: "memory");   // data in L2 (write-through ack)
            if (ln == 0)                                       // per-wave post (16/step)
                __hip_atomic_fetch_add(cell, 1u, __ATOMIC_RELAXED, __HIP_MEMORY_SCOPE_WORKGROUP);

            // prefetch P(t+1): lands during next poll (clamped at the tail)
            {
                int tn = (t + 1 < CH_) ? t + 1 : t;
                asm volatile("" ::: "memory");
                #pragma unroll
                for (int g = 0; g < 4; ++g)
                    #pragma unroll
                    for (int j = 0; j < 4; ++j)
                        pv[g][j] = Pbase[((long)tn * 64 + 4 * q + j) * G4_ + g * H_ + mycol];
                asm volatile("" ::: "memory");
            }
        }
    } else {
        // ============ FALLBACK: proven IC-scope protocol (round-7) ============
        #pragma unroll 1
        for (int t = 0; t < CH_; ++t) {
            const int gt = t0 + t;

            float pv[4][4];
            #pragma unroll
            for (int g = 0; g < 4; ++g)
                #pragma unroll
                for (int j = 0; j < 4; ++j)
                    pv[g][j] = Pbase[((long)t * 64 + 4 * q + j) * G4_ + g * H_ + mycol];
            asm volatile("" ::: "memory");

            {
                unsigned tgt = 4u * (unsigned)t, it = 0;
                while (__hip_atomic_load(cell, __ATOMIC_RELAXED, __HIP_MEMORY_SCOPE_AGENT) < tgt
                       && ++it < (1u << 18))
                    __builtin_amdgcn_s_sleep(1);
            }

            short8 ha[8], ca[8];
            if (gt == 0) {
                #pragma unroll
                for (int kt = 0; kt < 8; ++kt) {
                    #pragma unroll
                    for (int j = 0; j < 8; ++j) { ha[kt][j] = 0; ca[kt][j] = 0; }
                }
            } else {
                const unsigned short* crow = cx + ((long)(((gt - 1) & 1) * 8 + grp)) * 4096 + l16 * 256 + q * 8;
                const unsigned short* hrow = outp + ((long)(b0 + l16) * S_ + (gt - 1)) * H_ + q * 8;
                #pragma unroll
                for (int kt = 0; kt < 8; ++kt) ca[kt] = gload16_sc1(crow + kt * 32);
                #pragma unroll
                for (int kt = 0; kt < 8; ++kt) ha[kt] = gload16_sc1(hrow + kt * 32);
            }
            asm volatile("s_waitcnt vmcnt(8)" ::: "memory");
            __builtin_amdgcn_sched_barrier(0);

            f32x4 dacc = (f32x4){bdv, bdv, bdv, bdv};
            #pragma unroll
            for (int kt = 0; kt < 8; ++kt)
                dacc = __builtin_amdgcn_mfma_f32_16x16x32_bf16(ca[kt], wd[kt], dacc, 0, 0, 0);

            asm volatile("s_waitcnt vmcnt(0)" ::: "memory");
            __builtin_amdgcn_sched_barrier(0);

            f32x4 gacc[4];
            #pragma unroll
            for (int g = 0; g < 4; ++g) {
                gacc[g] = (f32x4){pv[g][0], pv[g][1], pv[g][2], pv[g][3]};
                #pragma unroll
                for (int kt = 0; kt < 8; ++kt)
                    gacc[g] = __builtin_amdgcn_mfma_f32_16x16x32_bf16(ha[kt], wg[g][kt], gacc[g], 0, 0, 0);
            }

            #pragma unroll
            for (int j = 0; j < 4; ++j) {
                int r = 4 * q + j;
                float tv = ts_lds[r][t];
                float cs1 = ftanh(dacc[j]);
                float cadj = cf[j] + cs1 * (tv - 1.0f);
                float fg = fsig(gacc[0][j]), ig = fsig(gacc[1][j]);
                float og = fsig(gacc[2][j]), ct = fsig(gacc[3][j]);
                float cn = fg * cadj + ig * ct;
                float hn = og * ftanh(cn);
                cf[j] = cn;
                gstore_short_sc1(outp + ((long)(b0 + r) * S_ + gt) * H_ + mycol, (unsigned)f2bf(hn));
                gstore_short_sc1(cx + ((long)((gt & 1) * 8 + grp)) * 4096 + r * 256 + mycol, (unsigned)f2bf(cn));
            }
            asm volatile("s_waitcnt vmcnt(0)" ::: "memory");
            __syncthreads();
            if (tid == 0) atomicAdd(cell, 1u);
        }
    }

    // persist fp32 c for next chunk
    #pragma unroll
    for (int j = 0; j < 4; ++j)
        cst[(long)(l * 4 + m) * 4096 + (4 * q + j) * 256 + mycol] = cf[j];
}

// ---------------------------------------------------------------- K4a: scores + softmax -> alpha
__global__ __launch_bounds__(512) void k4a_alpha(const unsigned short* __restrict__ out1,
                                                 const float* __restrict__ wa,
                                                 float* __restrict__ alpha) {
    __shared__ float sc[512];
    __shared__ float red[512];
    const int b = blockIdx.x, tid = threadIdx.x;
    const int w = tid >> 6, ln = tid & 63;
    f32x4 wv = *(const f32x4*)(wa + ln * 4);
    for (int i = 0; i < 64; ++i) {
        int s = w * 64 + i;
        const unsigned short* row = out1 + ((long)b * S_ + s) * H_ + ln * 4;
        float d = bf2f(row[0]) * wv[0] + bf2f(row[1]) * wv[1] +
                  bf2f(row[2]) * wv[2] + bf2f(row[3]) * wv[3];
        #pragma unroll
        for (int off = 32; off; off >>= 1) d += __shfl_xor(d, off);
        if (ln == 0) sc[s] = d;
    }
    __syncthreads();
    float v = sc[tid];
    red[tid] = v;
    for (int st = 256; st; st >>= 1) {
        __syncthreads();
        if (tid < st) red[tid] = fmaxf(red[tid], red[tid + st]);
    }
    __syncthreads();
    float M = red[0];
    __syncthreads();
    float e = __builtin_amdgcn_exp2f((v - M) * 1.44269504f);
    red[tid] = e;
    for (int st = 256; st; st >>= 1) {
        __syncthreads();
        if (tid < st) red[tid] += red[tid + st];
    }
    __syncthreads();
    alpha[b * S_ + tid] = e * __builtin_amdgcn_rcpf(red[0]);
}

// ---------------------------------------------------------------- K4b: Beta=tanh(out2@Wb^T); ctx = sum_s emb*Beta*alpha
__global__ __launch_bounds__(512, 2) void k4b_ctx(const unsigned short* __restrict__ out2,
                                                  const unsigned short* __restrict__ Wbb,
                                                  const unsigned short* __restrict__ embB,
                                                  const float* __restrict__ alpha,
                                                  float* __restrict__ ctx) {
    __shared__ float cbuf[32][256];
    const int b = blockIdx.x, tid = threadIdx.x;
    const int w = tid >> 6, ln = tid & 63, q = ln >> 4, l16 = ln & 15;

    float cp[16];
    #pragma unroll
    for (int nt = 0; nt < 16; ++nt) cp[nt] = 0.f;

    for (int i = 0; i < 4; ++i) {
        int mt = w * 4 + i;
        short8 af[8];
        #pragma unroll
        for (int kt = 0; kt < 8; ++kt)
            af[kt] = *(const short8*)(out2 + ((long)b * S_ + mt * 16 + l16) * H_ + kt * 32 + q * 8);
        float al[4];
        #pragma unroll
        for (int j = 0; j < 4; ++j) al[j] = alpha[b * S_ + mt * 16 + 4 * q + j];
        for (int nt = 0; nt < 16; ++nt) {
            f32x4 acc = (f32x4){0.f, 0.f, 0.f, 0.f};
            #pragma unroll
            for (int kt = 0; kt < 8; ++kt) {
                short8 bf = *(const short8*)(Wbb + (long)(nt * 16 + l16) * H_ + kt * 32 + q * 8);
                acc = __builtin_amdgcn_mfma_f32_16x16x32_bf16(af[kt], bf, acc, 0, 0, 0);
            }
            #pragma unroll
            for (int j = 0; j < 4; ++j) {
                int s = mt * 16 + 4 * q + j;
                float beta = ftanh(acc[j]);
                float ev = bf2f(embB[((long)b * S_ + s) * H_ + nt * 16 + l16]);
                cp[nt] += beta * al[j] * ev;
            }
        }
    }
    #pragma unroll
    for (int nt = 0; nt < 16; ++nt) cbuf[w * 4 + q][nt * 16 + l16] = cp[nt];
    __syncthreads();
    if (tid < 256) {
        float sum = 0.f;
        for (int i = 0; i < 32; ++i) sum += cbuf[i][tid];
        ctx[b * H_ + tid] = sum;
    }
}

// ---------------------------------------------------------------- K4c: out = ctx @ W_out^T
__global__ void k4c_out(const float* __restrict__ ctx, const float* __restrict__ Wout,
                        float* __restrict__ out) {
    int b = blockIdx.x, n = threadIdx.x;
    const f32x4* cr = (const f32x4*)(ctx + b * H_);
    const f32x4* wr = (const f32x4*)(Wout + n * H_);
    float acc = 0.f;
    #pragma unroll 8
    for (int i = 0; i < 64; ++i) {
        f32x4 c = cr[i], ww = wr[i];
        acc += c[0] * ww[0] + c[1] * ww[1] + c[2] * ww[2] + c[3] * ww[3];
    }
    out[b * NC_ + n] = acc;
}

// ---------------------------------------------------------------- launch
extern "C" void kernel_launch(void* const* d_in, const int* in_sizes, int n_in,
                              void* d_out, int out_size, void* d_ws, size_t ws_size,
                              hipStream_t stream) {
    (void)in_sizes; (void)n_in; (void)out_size; (void)ws_size;
    const float* inputs = (const float*)d_in[0];
    const float* tsp    = (const float*)d_in[1];
    const float* emb    = (const float*)d_in[2];
    const float* Wa1 = (const float*)d_in[3];  const float* ba1 = (const float*)d_in[4];
    const float* U1  = (const float*)d_in[5];  const float* bu1 = (const float*)d_in[6];
    const float* Wd1 = (const float*)d_in[7];  const float* bd1 = (const float*)d_in[8];
    const float* Wa2 = (const float*)d_in[9];  const float* ba2 = (const float*)d_in[10];
    const float* U2  = (const float*)d_in[11]; const float* bu2 = (const float*)d_in[12];
    const float* Wd2 = (const float*)d_in[13]; const float* bd2 = (const float*)d_in[14];
    const float* wa  = (const float*)d_in[15];
    const float* Wb  = (const float*)d_in[16];
    const float* Wout = (const float*)d_in[17];
    float* out = (float*)d_out;

    // Workspace map (round-11: cnt zone 24,576B).
    char* ws = (char*)d_ws;
    unsigned short* embT = (unsigned short*)(ws + 0);            //    720,896
    unsigned short* Wg   = (unsigned short*)(ws + 720896);       //  1,048,576 (Wd must follow)
    unsigned short* Wd   = (unsigned short*)(ws + 1769472);      //    262,144
    unsigned short* Ub   = (unsigned short*)(ws + 2031616);      //  1,048,576
    unsigned short* Wbb  = (unsigned short*)(ws + 3080192);      //    131,072
    float*          bgp  = (float*)(ws + 3211264);               //      8,192
    unsigned short* embB = (unsigned short*)(ws + 3219456);      // 16,777,216
    float*          P    = (float*)(ws + 19996672);              // 33,554,432 (64-step chunk)
    unsigned short* out1 = (unsigned short*)(ws + 53551104);     // 16,777,216
    unsigned short* out2 = (unsigned short*)(ws + 70328320);     // 16,777,216
    unsigned short* cx   = (unsigned short*)(ws + 87105536);     //    131,072 ([2 parity][8 grp][16][256] bf16)
    float*          cst  = (float*)(ws + 87236608);              //    131,072
    float*          alp  = (float*)(ws + 87367680);              //    131,072
    float*          ctx  = (float*)(ws + 87498752);              //     65,536
    unsigned int*   cnt  = (unsigned int*)(ws + 87564288);       //     24,576
    // total: 87,588,864 bytes (~83.5 MiB)

    hipLaunchKernelGGL(k0_prep, dim3(256), dim3(256), 0, stream,
                       emb, Wa1, Wa2, Wd1, Wd2, U1, U2, ba1, bu1, ba2, bu2, Wb,
                       embT, Wg, Wd, Ub, Wbb, bgp, cnt);
    hipLaunchKernelGGL(k1_embed, dim3(1024), dim3(512), 0, stream, inputs, embT, embB);
    for (int c = 0; c < 8; ++c) {
        hipLaunchKernelGGL(k2_pre, dim3(128), dim3(512), 0, stream, embB, Ub, bgp, P, c * CH_);
        hipLaunchKernelGGL(k3_lstm, dim3(32), dim3(256), 0, stream, tsp, Wg, bd1, bd2, P,
                           out1, out2, cst, cx, cnt, c * CH_);
    }
    hipLaunchKernelGGL(k4a_alpha, dim3(64), dim3(512), 0, stream, out1, wa, alp);
    hipLaunchKernelGGL(k4b_ctx, dim3(64), dim3(512), 0, stream, out2, Wbb, embB, alp, ctx);
    hipLaunchKernelGGL(k4c_out, dim3(64), dim3(128), 0, stream, ctx, Wout, out);
}

// Round 7
// 2822.438 us; speedup vs baseline: 2679.0976x; 1.0903x over previous
//
#include <hip/hip_runtime.h>

typedef __attribute__((ext_vector_type(8))) short short8;
typedef __attribute__((ext_vector_type(4))) float f32x4;
typedef __attribute__((ext_vector_type(4))) unsigned int u32x4;

#define B_   64
#define S_   512
#define V_   1400
#define VP_  1408
#define H_   256
#define G4_  1024
#define NC_  128
#define CH_  64    // time-chunk length (8 chunks of 64 steps)

__device__ __forceinline__ unsigned short f2bf(float f) {
    unsigned u = __builtin_bit_cast(unsigned, f);
    u += 0x7FFFu + ((u >> 16) & 1u);
    return (unsigned short)(u >> 16);
}
__device__ __forceinline__ float bf2f(unsigned short h) {
    unsigned u = ((unsigned)h) << 16;
    return __builtin_bit_cast(float, u);
}
__device__ __forceinline__ float fsig(float x) {
    x = fminf(fmaxf(x, -40.f), 40.f);
    float e = __builtin_amdgcn_exp2f(x * -1.44269504f);
    return __builtin_amdgcn_rcpf(1.0f + e);
}
__device__ __forceinline__ float ftanh(float x) {
    x = fminf(fmaxf(x, -40.f), 40.f);
    float e = __builtin_amdgcn_exp2f(x * 2.88539008f);
    return 1.0f - 2.0f * __builtin_amdgcn_rcpf(e + 1.0f);
}

// ---- IC-coherent (cross-XCD) primitives — proven fallback path ----
__device__ __forceinline__ short8 gload16_sc1(const unsigned short* p) {
    short8 r;
    asm volatile("global_load_dwordx4 %0, %1, off sc1"
                 : "=&v"(r) : "v"((unsigned long long)p));
    return r;
}
__device__ __forceinline__ void gstore_short_sc1(unsigned short* p, unsigned v) {
    asm volatile("global_store_short %0, %1, off sc1"
                 :: "v"((unsigned long long)p), "v"(v));
}
// ---- L2-local (same-XCD) primitives — fast path ----
__device__ __forceinline__ short8 gload16_sc0(const unsigned short* p) {
    short8 r;
    asm volatile("global_load_dwordx4 %0, %1, off sc0"
                 : "=&v"(r) : "v"((unsigned long long)p));
    return r;
}
__device__ __forceinline__ void gstore_short_plain(unsigned short* p, unsigned v) {
    asm volatile("global_store_short %0, %1, off"
                 :: "v"((unsigned long long)p), "v"(v));
}
__device__ __forceinline__ void gstore_dword_plain(unsigned int* p, unsigned v) {
    asm volatile("global_store_dword %0, %1, off"
                 :: "v"((unsigned long long)p), "v"(v));
}
// one-shot 16-flag read: 4x dwordx4 PLAIN + vmcnt drain. The target line is
// per-(chunk,step)-unique and the per-step buffer_inv ran => guaranteed L1
// miss => served by the shared XCD L2 (the proven data-visibility path).
__device__ __forceinline__ void gpoll16_plain(const unsigned int* p,
                                              u32x4& f0, u32x4& f1, u32x4& f2, u32x4& f3) {
    asm volatile("global_load_dwordx4 %0, %4, off\n\t"
                 "global_load_dwordx4 %1, %5, off\n\t"
                 "global_load_dwordx4 %2, %6, off\n\t"
                 "global_load_dwordx4 %3, %7, off\n\t"
                 "s_waitcnt vmcnt(0)"
                 : "=&v"(f0), "=&v"(f1), "=&v"(f2), "=&v"(f3)
                 : "v"((unsigned long long)p),        "v"((unsigned long long)(p + 4)),
                   "v"((unsigned long long)(p + 8)),  "v"((unsigned long long)(p + 12)));
}

// cnt zone layout (ints): step counters (chunk*8+grp)*64  [0,4096)
//                         rdy[chunk] at 4096+chunk*64     [4096,4608)
//                         xpub[32]   at 4608              [4608,4640)
//                         spec flags at 6144+(chunk*64+t)*64, 16 dwords/line
#define CNT_ZONE_ 38912   // 6144 + 8*64*64 dwords

// ---------------------------------------------------------------- K0: prep
__global__ void k0_prep(const float* __restrict__ emb,
                        const float* __restrict__ Wa1, const float* __restrict__ Wa2,
                        const float* __restrict__ Wd1, const float* __restrict__ Wd2,
                        const float* __restrict__ U1,  const float* __restrict__ U2,
                        const float* __restrict__ ba1, const float* __restrict__ bu1,
                        const float* __restrict__ ba2, const float* __restrict__ bu2,
                        const float* __restrict__ Wb,
                        unsigned short* __restrict__ embT, unsigned short* __restrict__ Wg,
                        unsigned short* __restrict__ Wd,   unsigned short* __restrict__ Ub,
                        unsigned short* __restrict__ Wbb,  float* __restrict__ bg,
                        unsigned int* __restrict__ cnt) {
    int tid = blockIdx.x * blockDim.x + threadIdx.x;
    int np = gridDim.x * blockDim.x;
    for (int i = tid; i < 256 * VP_; i += np) {
        int n = i / VP_, k = i - n * VP_;
        embT[i] = (k < V_) ? f2bf(emb[k * H_ + n]) : (unsigned short)0;
    }
    for (int i = tid; i < G4_ * H_; i += np) {
        Wg[i] = f2bf(Wa1[i]); Wg[G4_ * H_ + i] = f2bf(Wa2[i]);
        Ub[i] = f2bf(U1[i]);  Ub[G4_ * H_ + i] = f2bf(U2[i]);
    }
    for (int i = tid; i < H_ * H_; i += np) {
        Wd[i] = f2bf(Wd1[i]); Wd[H_ * H_ + i] = f2bf(Wd2[i]); Wbb[i] = f2bf(Wb[i]);
    }
    for (int i = tid; i < G4_; i += np) {
        bg[i] = ba1[i] + bu1[i]; bg[G4_ + i] = ba2[i] + bu2[i];
    }
    for (int i = tid; i < CNT_ZONE_; i += np) cnt[i] = 0;   // counters + flags, re-zeroed every run
}

// ---------------------------------------------------------------- K1: embedded = inputs @ emb
__global__ __launch_bounds__(512, 2) void k1_embed(const float* __restrict__ inputs,
                                                   const unsigned short* __restrict__ embT,
                                                   unsigned short* __restrict__ embB) {
    const int tid = threadIdx.x;
    const int w = tid >> 6, ln = tid & 63, q = ln >> 4, l16 = ln & 15;
    const int mt = w >> 2, ng = (w & 3) * 4;
    const int Rbase = blockIdx.x * 32 + mt * 16;
    const float* arow = inputs + (long)(Rbase + l16) * V_;

    f32x4 acc[4];
    #pragma unroll
    for (int i = 0; i < 4; ++i) acc[i] = (f32x4){0.f, 0.f, 0.f, 0.f};

    for (int kt = 0; kt < 44; ++kt) {
        int k0 = kt * 32 + q * 8;
        short8 af;
        if (kt == 43 && q == 3) {
            #pragma unroll
            for (int j = 0; j < 8; ++j) af[j] = 0;
        } else {
            f32x4 x0 = *(const f32x4*)(arow + k0);
            f32x4 x1 = *(const f32x4*)(arow + k0 + 4);
            #pragma unroll
            for (int j = 0; j < 4; ++j) { af[j] = (short)f2bf(x0[j]); af[4 + j] = (short)f2bf(x1[j]); }
        }
        #pragma unroll
        for (int i = 0; i < 4; ++i) {
            short8 bf = *(const short8*)(embT + (long)((ng + i) * 16 + l16) * VP_ + k0);
            acc[i] = __builtin_amdgcn_mfma_f32_16x16x32_bf16(af, bf, acc[i], 0, 0, 0);
        }
    }
    #pragma unroll
    for (int i = 0; i < 4; ++i) {
        int col = (ng + i) * 16 + l16;
        #pragma unroll
        for (int j = 0; j < 4; ++j) {
            int R = Rbase + 4 * q + j;
            embB[(long)R * H_ + col] = f2bf(acc[i][j]);
        }
    }
}

// ---------------------------------------------------------------- K2: P chunk = embedded @ [U1;U2]^T + bg
// (used for the chunk-0 prologue and the no-fuse fallback path)
__global__ __launch_bounds__(512, 2) void k2_pre(const unsigned short* __restrict__ embB,
                                                 const unsigned short* __restrict__ Ub,
                                                 const float* __restrict__ bg,
                                                 float* __restrict__ P, int t0) {
    const int tid = threadIdx.x;
    const int w = tid >> 6, ln = tid & 63, q = ln >> 4, l16 = ln & 15;
    const int rbase = blockIdx.x * 32;  // local row' in chunk, 0..4095

    short8 af[2][8];
    #pragma unroll
    for (int mt = 0; mt < 2; ++mt)
        #pragma unroll
        for (int kt = 0; kt < 8; ++kt) {
            int rp = rbase + mt * 16 + l16;
            int rg = t0 * 64 + rp;
            int b = rg & 63, s = rg >> 6;
            af[mt][kt] = *(const short8*)(embB + ((long)b * S_ + s) * H_ + kt * 32 + q * 8);
        }

    for (int i = 0; i < 16; ++i) {
        int nt2 = w * 16 + i;          // global gate-col tile 0..127
        int l = nt2 >> 6;
        int gcol = (nt2 & 63) * 16 + l16;   // col within lstm, 0..1023
        float bias = bg[nt2 * 16 + l16];
        short8 bf[8];
        #pragma unroll
        for (int kt = 0; kt < 8; ++kt)
            bf[kt] = *(const short8*)(Ub + (long)(nt2 * 16 + l16) * H_ + kt * 32 + q * 8);
        #pragma unroll
        for (int mt = 0; mt < 2; ++mt) {
            f32x4 acc = (f32x4){bias, bias, bias, bias};
            #pragma unroll
            for (int kt = 0; kt < 8; ++kt)
                acc = __builtin_amdgcn_mfma_f32_16x16x32_bf16(af[mt][kt], bf[kt], acc, 0, 0, 0);
            int rp0 = rbase + mt * 16;
            float* dst = P + ((long)l * (CH_ * 64) + rp0 + 4 * q) * G4_ + gcol;
            #pragma unroll
            for (int j = 0; j < 4; ++j) dst[(long)j * G4_] = acc[j];
        }
    }
}

// ---------------------------------------------------------------- K3: fused LSTM chunk + next-chunk P GEMM
// Round-12:
//  (a) Fused dual-role dispatch: blocks 0..31 = LSTM(chunk c) reading Pcur;
//      blocks 32..287 = 4-wave k2 port computing P(chunk c+1) into Pnext
//      (double-buffered). Removes 8 serial k2 dispatches; cross-dispatch
//      visibility is the same boundary guarantee k2->k3 already used.
//  (b) Speculative per-step flag lines take the IC-latency counter RMW off the
//      common poll path (round-6 model: ALL atomics execute at the IC; the
//      shared ~3us/step was post+poll IC RTs + 16-poller same-line RMW
//      serialization). Posters plain-store 1 into their dword of a fresh
//      256B line after the data drain (L2-visible, the proven path) and
//      fire-and-forget a counter add; pollers read the line ONCE (per-step-
//      unique address + per-step buffer_inv => guaranteed L1 miss => current
//      L2 data). Not-all-set => round-6 RMW fallback (correctness never
//      depends on the speculative read).
__global__ __launch_bounds__(256, 1) void k3_fused(const float* __restrict__ ts,
                                                   const unsigned short* __restrict__ W, // Wg || Wd
                                                   const float* __restrict__ bd1,
                                                   const float* __restrict__ bd2,
                                                   const float* __restrict__ Pcur,
                                                   unsigned short* __restrict__ out1,
                                                   unsigned short* __restrict__ out2,
                                                   float* __restrict__ cst,
                                                   unsigned short* __restrict__ cx,
                                                   unsigned int* __restrict__ cnt,
                                                   int t0,
                                                   const unsigned short* __restrict__ embB,
                                                   const unsigned short* __restrict__ Ub,
                                                   const float* __restrict__ bg,
                                                   float* __restrict__ Pnext,
                                                   int next_t0) {
    const int tid = threadIdx.x;
    const int w = tid >> 6, ln = tid & 63, q = ln >> 4, l16 = ln & 15;
    const int bid = blockIdx.x;

    if (bid >= 32) {
        // ================= GEMM role: P(next chunk) = embB @ Ub^T + bg =======
        const int g2 = bid - 32;
        const int rbase = (g2 >> 1) * 32;
        const int hb = g2 & 1;

        short8 af[2][8];
        #pragma unroll
        for (int mt = 0; mt < 2; ++mt)
            #pragma unroll
            for (int kt = 0; kt < 8; ++kt) {
                int rp = rbase + mt * 16 + l16;
                int rg = next_t0 * 64 + rp;
                int b = rg & 63, s = rg >> 6;
                af[mt][kt] = *(const short8*)(embB + ((long)b * S_ + s) * H_ + kt * 32 + q * 8);
            }

        for (int i = 0; i < 16; ++i) {
            int nt2 = hb * 64 + w * 16 + i;
            int l = nt2 >> 6;
            int gcol = (nt2 & 63) * 16 + l16;
            float bias = bg[nt2 * 16 + l16];
            short8 bf[8];
            #pragma unroll
            for (int kt = 0; kt < 8; ++kt)
                bf[kt] = *(const short8*)(Ub + (long)(nt2 * 16 + l16) * H_ + kt * 32 + q * 8);
            #pragma unroll
            for (int mt = 0; mt < 2; ++mt) {
                f32x4 acc = (f32x4){bias, bias, bias, bias};
                #pragma unroll
                for (int kt = 0; kt < 8; ++kt)
                    acc = __builtin_amdgcn_mfma_f32_16x16x32_bf16(af[mt][kt], bf[kt], acc, 0, 0, 0);
                int rp0 = rbase + mt * 16;
                float* dst = Pnext + ((long)l * (CH_ * 64) + rp0 + 4 * q) * G4_ + gcol;
                #pragma unroll
                for (int j = 0; j < 4; ++j) dst[(long)j * G4_] = acc[j];
            }
        }
        return;
    }

    // ==================== LSTM role (blocks 0..31) ===========================
    __shared__ float ts_lds[16][CH_];
    const int chunk = t0 >> 6;

    // -------- XCD discovery (IC-scope handshake, once per launch) ------------
    const int myx = (int)__builtin_amdgcn_s_getreg(63508);  // HW_REG_XCC_ID
    unsigned int* rdy  = cnt + 4096 + chunk * 64;
    int*          xpub = (int*)(cnt + 4608);
    if (tid == 0) {
        __hip_atomic_store(&xpub[bid], myx, __ATOMIC_RELAXED, __HIP_MEMORY_SCOPE_AGENT);
        __hip_atomic_fetch_add(rdy, 1u, __ATOMIC_RELEASE, __HIP_MEMORY_SCOPE_AGENT);
    }
    unsigned hs_it = 0;
    while (__hip_atomic_load(rdy, __ATOMIC_ACQUIRE, __HIP_MEMORY_SCOPE_AGENT) < 32u
           && ++hs_it < (1u << 20))
        __builtin_amdgcn_s_sleep(2);
    int xv[32];
    #pragma unroll
    for (int i = 0; i < 32; ++i)
        xv[i] = __hip_atomic_load(&xpub[i], __ATOMIC_RELAXED, __HIP_MEMORY_SCOPE_AGENT);
    unsigned okA = 1, inr = 1, mask = 0;
    #pragma unroll
    for (int g = 0; g < 8; ++g)
        okA &= (unsigned)((xv[g] == xv[g + 8]) & (xv[g] == xv[g + 16]) & (xv[g] == xv[g + 24]));
    #pragma unroll
    for (int i = 0; i < 32; ++i) {
        inr &= (unsigned)((unsigned)xv[i] < 8u);
        mask |= 1u << ((unsigned)xv[i] & 31u);
    }
    const bool fast = okA && inr && (mask == 0xFFu) && (hs_it < (1u << 20));

    // -------- role decode ----------------------------------------------------
    const int grp = bid & 7, cg = bid >> 3;    // mapping A: {g,g+8,g+16,g+24} co-XCD
    const int l = grp >> 2, m = grp & 3, b0 = m * 16;
    const int hc0 = cg * 64 + w * 16;
    const int mycol = hc0 + l16;
    unsigned int* cell = cnt + (chunk * 8 + grp) * 64;   // fallback/RMW counter
    unsigned int* fbase = cnt + 6144 + (long)chunk * 64 * 64;  // spec flag lines
    unsigned short* outp = l ? out2 : out1;
    const float bdv = (l ? bd2 : bd1)[mycol];

    for (int i = tid; i < 16 * CH_; i += 256) {
        int r = i >> 6, cc = i & (CH_ - 1);
        ts_lds[r][cc] = ts[(b0 + r) * S_ + t0 + cc];
    }

    // -------- register/AGPR-resident weights (loaded once per launch) --------
    short8 wg[4][8];
    short8 wd[8];
    #pragma unroll
    for (int g = 0; g < 4; ++g)
        #pragma unroll
        for (int kt = 0; kt < 8; ++kt)
            wg[g][kt] = *(const short8*)(W + ((long)(l * G4_ + g * H_ + mycol)) * H_ + kt * 32 + q * 8);
    #pragma unroll
    for (int kt = 0; kt < 8; ++kt)
        wd[kt] = *(const short8*)(W + (long)2 * G4_ * H_ + ((long)(l * H_ + mycol)) * H_ + kt * 32 + q * 8);

    float cf[4];
    if (t0 == 0) {
        cf[0] = cf[1] = cf[2] = cf[3] = 0.f;
    } else {
        #pragma unroll
        for (int j = 0; j < 4; ++j)
            cf[j] = cst[(long)(l * 4 + m) * 4096 + (4 * q + j) * 256 + mycol];
    }
    __syncthreads();   // ts_lds ready

    const float* Pbase = Pcur + ((long)l * (CH_ * 64) + b0) * G4_;

    if (fast) {
        // ================= FAST: same-XCD, L2-scope protocol =================
        unsigned opaque_zero;
        asm volatile("v_mov_b32 %0, 0" : "=v"(opaque_zero));

        float pv[4][4];
        #pragma unroll
        for (int g = 0; g < 4; ++g)
            #pragma unroll
            for (int j = 0; j < 4; ++j)
                pv[g][j] = Pbase[((long)(4 * q + j)) * G4_ + g * H_ + mycol];
        asm volatile("" ::: "memory");

        #pragma unroll 1
        for (int t = 0; t < CH_; ++t) {
            const int gt = t0 + t;

            if (t) {
                // speculative flag-line read (fresh address => L2-current)
                const unsigned int* fprev = fbase + (long)(t - 1) * 64;
                u32x4 f0, f1, f2, f3;
                gpoll16_plain(fprev, f0, f1, f2, f3);
                unsigned s = 0;
                #pragma unroll
                for (int i = 0; i < 4; ++i) s += f0[i] + f1[i] + f2[i] + f3[i];
                if (s != 16u) {
                    // RMW fallback at the atomics' execution point (round-6 proven)
                    const unsigned tgt = 16u * (unsigned)t;
                    unsigned it = 0;
                    for (;;) {
                        unsigned v = 0;
                        if (ln == 0)
                            v = __hip_atomic_fetch_add(cell, opaque_zero,
                                                       __ATOMIC_RELAXED, __HIP_MEMORY_SCOPE_WORKGROUP);
                        v = __shfl(v, 0);
                        if (v >= tgt || ++it >= (1u << 14)) break;
                    }
                }
            }
            // acquire: invalidate L1 so gathers (and reused out-row lines) are fresh
            __builtin_amdgcn_fence(__ATOMIC_ACQUIRE, "agent");
            __builtin_amdgcn_sched_barrier(0);

            short8 ha[8], ca[8];
            if (gt == 0) {
                #pragma unroll
                for (int kt = 0; kt < 8; ++kt) {
                    #pragma unroll
                    for (int j = 0; j < 8; ++j) { ha[kt][j] = 0; ca[kt][j] = 0; }
                }
            } else {
                const unsigned short* crow = cx + ((long)(((gt - 1) & 1) * 8 + grp)) * 4096 + l16 * 256 + q * 8;
                const unsigned short* hrow = outp + ((long)(b0 + l16) * S_ + (gt - 1)) * H_ + q * 8;
                #pragma unroll
                for (int kt = 0; kt < 8; ++kt) ca[kt] = gload16_sc0(crow + kt * 32);
                #pragma unroll
                for (int kt = 0; kt < 8; ++kt) ha[kt] = gload16_sc0(hrow + kt * 32);
            }
            asm volatile("s_waitcnt vmcnt(8)" ::: "memory");   // ca complete
            __builtin_amdgcn_sched_barrier(0);

            f32x4 dacc = (f32x4){bdv, bdv, bdv, bdv};
            #pragma unroll
            for (int kt = 0; kt < 8; ++kt)
                dacc = __builtin_amdgcn_mfma_f32_16x16x32_bf16(ca[kt], wd[kt], dacc, 0, 0, 0);

            asm volatile("s_waitcnt vmcnt(0)" ::: "memory");   // ha complete
            __builtin_amdgcn_sched_barrier(0);

            f32x4 gacc[4];
            #pragma unroll
            for (int g = 0; g < 4; ++g) {
                gacc[g] = (f32x4){pv[g][0], pv[g][1], pv[g][2], pv[g][3]};
                #pragma unroll
                for (int kt = 0; kt < 8; ++kt)
                    gacc[g] = __builtin_amdgcn_mfma_f32_16x16x32_bf16(ha[kt], wg[g][kt], gacc[g], 0, 0, 0);
            }

            #pragma unroll
            for (int j = 0; j < 4; ++j) {
                int r = 4 * q + j;
                float tv = ts_lds[r][t];
                float cs1 = ftanh(dacc[j]);
                float cadj = cf[j] + cs1 * (tv - 1.0f);
                float fg = fsig(gacc[0][j]), ig = fsig(gacc[1][j]);
                float og = fsig(gacc[2][j]), ct = fsig(gacc[3][j]);
                float cn = fg * cadj + ig * ct;
                float hn = og * ftanh(cn);
                cf[j] = cn;
                gstore_short_plain(outp + ((long)(b0 + r) * S_ + gt) * H_ + mycol, (unsigned)f2bf(hn));
                gstore_short_plain(cx + ((long)((gt & 1) * 8 + grp)) * 4096 + r * 256 + mycol, (unsigned)f2bf(cn));
            }
            asm volatile("s_waitcnt vmcnt(0)" ::: "memory");   // data ack'd in L2
            if (ln == 0) {
                // spec flag (L2, read by next step's one-shot poll) ...
                gstore_dword_plain(fbase + (long)t * 64 + (cg * 4 + w), 1u);
                // ... and fire-and-forget counter add for the RMW fallback
                (void)__hip_atomic_fetch_add(cell, 1u, __ATOMIC_RELAXED, __HIP_MEMORY_SCOPE_WORKGROUP);
            }

            // prefetch P(t+1): lands during next poll (clamped at the tail)
            {
                int tn = (t + 1 < CH_) ? t + 1 : t;
                asm volatile("" ::: "memory");
                #pragma unroll
                for (int g = 0; g < 4; ++g)
                    #pragma unroll
                    for (int j = 0; j < 4; ++j)
                        pv[g][j] = Pbase[((long)tn * 64 + 4 * q + j) * G4_ + g * H_ + mycol];
                asm volatile("" ::: "memory");
            }
        }
    } else {
        // ============ FALLBACK: proven IC-scope protocol (round-7) ============
        #pragma unroll 1
        for (int t = 0; t < CH_; ++t) {
            const int gt = t0 + t;

            float pv[4][4];
            #pragma unroll
            for (int g = 0; g < 4; ++g)
                #pragma unroll
                for (int j = 0; j < 4; ++j)
                    pv[g][j] = Pbase[((long)t * 64 + 4 * q + j) * G4_ + g * H_ + mycol];
            asm volatile("" ::: "memory");

            {
                unsigned tgt = 4u * (unsigned)t, it = 0;
                while (__hip_atomic_load(cell, __ATOMIC_RELAXED, __HIP_MEMORY_SCOPE_AGENT) < tgt
                       && ++it < (1u << 18))
                    __builtin_amdgcn_s_sleep(1);
            }

            short8 ha[8], ca[8];
            if (gt == 0) {
                #pragma unroll
                for (int kt = 0; kt < 8; ++kt) {
                    #pragma unroll
                    for (int j = 0; j < 8; ++j) { ha[kt][j] = 0; ca[kt][j] = 0; }
                }
            } else {
                const unsigned short* crow = cx + ((long)(((gt - 1) & 1) * 8 + grp)) * 4096 + l16 * 256 + q * 8;
                const unsigned short* hrow = outp + ((long)(b0 + l16) * S_ + (gt - 1)) * H_ + q * 8;
                #pragma unroll
                for (int kt = 0; kt < 8; ++kt) ca[kt] = gload16_sc1(crow + kt * 32);
                #pragma unroll
                for (int kt = 0; kt < 8; ++kt) ha[kt] = gload16_sc1(hrow + kt * 32);
            }
            asm volatile("s_waitcnt vmcnt(8)" ::: "memory");
            __builtin_amdgcn_sched_barrier(0);

            f32x4 dacc = (f32x4){bdv, bdv, bdv, bdv};
            #pragma unroll
            for (int kt = 0; kt < 8; ++kt)
                dacc = __builtin_amdgcn_mfma_f32_16x16x32_bf16(ca[kt], wd[kt], dacc, 0, 0, 0);

            asm volatile("s_waitcnt vmcnt(0)" ::: "memory");
            __builtin_amdgcn_sched_barrier(0);

            f32x4 gacc[4];
            #pragma unroll
            for (int g = 0; g < 4; ++g) {
                gacc[g] = (f32x4){pv[g][0], pv[g][1], pv[g][2], pv[g][3]};
                #pragma unroll
                for (int kt = 0; kt < 8; ++kt)
                    gacc[g] = __builtin_amdgcn_mfma_f32_16x16x32_bf16(ha[kt], wg[g][kt], gacc[g], 0, 0, 0);
            }

            #pragma unroll
            for (int j = 0; j < 4; ++j) {
                int r = 4 * q + j;
                float tv = ts_lds[r][t];
                float cs1 = ftanh(dacc[j]);
                float cadj = cf[j] + cs1 * (tv - 1.0f);
                float fg = fsig(gacc[0][j]), ig = fsig(gacc[1][j]);
                float og = fsig(gacc[2][j]), ct = fsig(gacc[3][j]);
                float cn = fg * cadj + ig * ct;
                float hn = og * ftanh(cn);
                cf[j] = cn;
                gstore_short_sc1(outp + ((long)(b0 + r) * S_ + gt) * H_ + mycol, (unsigned)f2bf(hn));
                gstore_short_sc1(cx + ((long)((gt & 1) * 8 + grp)) * 4096 + r * 256 + mycol, (unsigned)f2bf(cn));
            }
            asm volatile("s_waitcnt vmcnt(0)" ::: "memory");
            __syncthreads();
            if (tid == 0) atomicAdd(cell, 1u);
        }
    }

    // persist fp32 c for next chunk
    #pragma unroll
    for (int j = 0; j < 4; ++j)
        cst[(long)(l * 4 + m) * 4096 + (4 * q + j) * 256 + mycol] = cf[j];
}

// ---------------------------------------------------------------- K4a: scores + softmax -> alpha
__global__ __launch_bounds__(512) void k4a_alpha(const unsigned short* __restrict__ out1,
                                                 const float* __restrict__ wa,
                                                 float* __restrict__ alpha) {
    __shared__ float sc[512];
    __shared__ float red[512];
    const int b = blockIdx.x, tid = threadIdx.x;
    const int w = tid >> 6, ln = tid & 63;
    f32x4 wv = *(const f32x4*)(wa + ln * 4);
    for (int i = 0; i < 64; ++i) {
        int s = w * 64 + i;
        const unsigned short* row = out1 + ((long)b * S_ + s) * H_ + ln * 4;
        float d = bf2f(row[0]) * wv[0] + bf2f(row[1]) * wv[1] +
                  bf2f(row[2]) * wv[2] + bf2f(row[3]) * wv[3];
        #pragma unroll
        for (int off = 32; off; off >>= 1) d += __shfl_xor(d, off);
        if (ln == 0) sc[s] = d;
    }
    __syncthreads();
    float v = sc[tid];
    red[tid] = v;
    for (int st = 256; st; st >>= 1) {
        __syncthreads();
        if (tid < st) red[tid] = fmaxf(red[tid], red[tid + st]);
    }
    __syncthreads();
    float M = red[0];
    __syncthreads();
    float e = __builtin_amdgcn_exp2f((v - M) * 1.44269504f);
    red[tid] = e;
    for (int st = 256; st; st >>= 1) {
        __syncthreads();
        if (tid < st) red[tid] += red[tid + st];
    }
    __syncthreads();
    alpha[b * S_ + tid] = e * __builtin_amdgcn_rcpf(red[0]);
}

// ---------------------------------------------------------------- K4b: Beta=tanh(out2@Wb^T); ctx = sum_s emb*Beta*alpha
__global__ __launch_bounds__(512, 2) void k4b_ctx(const unsigned short* __restrict__ out2,
                                                  const unsigned short* __restrict__ Wbb,
                                                  const unsigned short* __restrict__ embB,
                                                  const float* __restrict__ alpha,
                                                  float* __restrict__ ctx) {
    __shared__ float cbuf[32][256];
    const int b = blockIdx.x, tid = threadIdx.x;
    const int w = tid >> 6, ln = tid & 63, q = ln >> 4, l16 = ln & 15;

    float cp[16];
    #pragma unroll
    for (int nt = 0; nt < 16; ++nt) cp[nt] = 0.f;

    for (int i = 0; i < 4; ++i) {
        int mt = w * 4 + i;
        short8 af[8];
        #pragma unroll
        for (int kt = 0; kt < 8; ++kt)
            af[kt] = *(const short8*)(out2 + ((long)b * S_ + mt * 16 + l16) * H_ + kt * 32 + q * 8);
        float al[4];
        #pragma unroll
        for (int j = 0; j < 4; ++j) al[j] = alpha[b * S_ + mt * 16 + 4 * q + j];
        for (int nt = 0; nt < 16; ++nt) {
            f32x4 acc = (f32x4){0.f, 0.f, 0.f, 0.f};
            #pragma unroll
            for (int kt = 0; kt < 8; ++kt) {
                short8 bf = *(const short8*)(Wbb + (long)(nt * 16 + l16) * H_ + kt * 32 + q * 8);
                acc = __builtin_amdgcn_mfma_f32_16x16x32_bf16(af[kt], bf, acc, 0, 0, 0);
            }
            #pragma unroll
            for (int j = 0; j < 4; ++j) {
                int s = mt * 16 + 4 * q + j;
                float beta = ftanh(acc[j]);
                float ev = bf2f(embB[((long)b * S_ + s) * H_ + nt * 16 + l16]);
                cp[nt] += beta * al[j] * ev;
            }
        }
    }
    #pragma unroll
    for (int nt = 0; nt < 16; ++nt) cbuf[w * 4 + q][nt * 16 + l16] = cp[nt];
    __syncthreads();
    if (tid < 256) {
        float sum = 0.f;
        for (int i = 0; i < 32; ++i) sum += cbuf[i][tid];
        ctx[b * H_ + tid] = sum;
    }
}

// ---------------------------------------------------------------- K4c: out = ctx @ W_out^T
__global__ void k4c_out(const float* __restrict__ ctx, const float* __restrict__ Wout,
                        float* __restrict__ out) {
    int b = blockIdx.x, n = threadIdx.x;
    const f32x4* cr = (const f32x4*)(ctx + b * H_);
    const f32x4* wr = (const f32x4*)(Wout + n * H_);
    float acc = 0.f;
    #pragma unroll 8
    for (int i = 0; i < 64; ++i) {
        f32x4 c = cr[i], ww = wr[i];
        acc += c[0] * ww[0] + c[1] * ww[1] + c[2] * ww[2] + c[3] * ww[3];
    }
    out[b * NC_ + n] = acc;
}

// ---------------------------------------------------------------- launch
extern "C" void kernel_launch(void* const* d_in, const int* in_sizes, int n_in,
                              void* d_out, int out_size, void* d_ws, size_t ws_size,
                              hipStream_t stream) {
    (void)in_sizes; (void)n_in; (void)out_size;
    const float* inputs = (const float*)d_in[0];
    const float* tsp    = (const float*)d_in[1];
    const float* emb    = (const float*)d_in[2];
    const float* Wa1 = (const float*)d_in[3];  const float* ba1 = (const float*)d_in[4];
    const float* U1  = (const float*)d_in[5];  const float* bu1 = (const float*)d_in[6];
    const float* Wd1 = (const float*)d_in[7];  const float* bd1 = (const float*)d_in[8];
    const float* Wa2 = (const float*)d_in[9];  const float* ba2 = (const float*)d_in[10];
    const float* U2  = (const float*)d_in[11]; const float* bu2 = (const float*)d_in[12];
    const float* Wd2 = (const float*)d_in[13]; const float* bd2 = (const float*)d_in[14];
    const float* wa  = (const float*)d_in[15];
    const float* Wb  = (const float*)d_in[16];
    const float* Wout = (const float*)d_in[17];
    float* out = (float*)d_out;

    // Workspace map (round-12: cnt zone 155,648B = counters + 8x64 spec flag
    // lines; optional second P buffer for the fused-GEMM path).
    char* ws = (char*)d_ws;
    unsigned short* embT = (unsigned short*)(ws + 0);            //    720,896
    unsigned short* Wg   = (unsigned short*)(ws + 720896);       //  1,048,576 (Wd must follow)
    unsigned short* Wd   = (unsigned short*)(ws + 1769472);      //    262,144
    unsigned short* Ub   = (unsigned short*)(ws + 2031616);      //  1,048,576
    unsigned short* Wbb  = (unsigned short*)(ws + 3080192);      //    131,072
    float*          bgp  = (float*)(ws + 3211264);               //      8,192
    unsigned short* embB = (unsigned short*)(ws + 3219456);      // 16,777,216
    float*          P0   = (float*)(ws + 19996672);              // 33,554,432
    unsigned short* out1 = (unsigned short*)(ws + 53551104);     // 16,777,216
    unsigned short* out2 = (unsigned short*)(ws + 70328320);     // 16,777,216
    unsigned short* cx   = (unsigned short*)(ws + 87105536);     //    131,072
    float*          cst  = (float*)(ws + 87236608);              //    131,072
    float*          alp  = (float*)(ws + 87367680);              //    131,072
    float*          ctx  = (float*)(ws + 87498752);              //     65,536
    unsigned int*   cnt  = (unsigned int*)(ws + 87564288);       //    155,648
    float*          P1   = (float*)(ws + 87719936);              // 33,554,432 (fused path only)
    const size_t NEED_FUSED = 121274368;                         // 87,719,936 + 33,554,432
    const bool fuse = (ws_size >= NEED_FUSED);

    hipLaunchKernelGGL(k0_prep, dim3(256), dim3(256), 0, stream,
                       emb, Wa1, Wa2, Wd1, Wd2, U1, U2, ba1, bu1, ba2, bu2, Wb,
                       embT, Wg, Wd, Ub, Wbb, bgp, cnt);
    hipLaunchKernelGGL(k1_embed, dim3(1024), dim3(512), 0, stream, inputs, embT, embB);
    // prologue: P(chunk 0)
    hipLaunchKernelGGL(k2_pre, dim3(128), dim3(512), 0, stream, embB, Ub, bgp, P0, 0);

    float* Pb[2] = { P0, fuse ? P1 : P0 };
    for (int c = 0; c < 8; ++c) {
        if (fuse) {
            int ng = (c < 7) ? 256 : 0;
            hipLaunchKernelGGL(k3_fused, dim3(32 + ng), dim3(256), 0, stream,
                               tsp, Wg, bd1, bd2, Pb[c & 1], out1, out2, cst, cx, cnt, c * CH_,
                               embB, Ub, bgp, Pb[(c + 1) & 1], (c + 1) * CH_);
        } else {
            if (c > 0)
                hipLaunchKernelGGL(k2_pre, dim3(128), dim3(512), 0, stream, embB, Ub, bgp, P0, c * CH_);
            hipLaunchKernelGGL(k3_fused, dim3(32), dim3(256), 0, stream,
                               tsp, Wg, bd1, bd2, P0, out1, out2, cst, cx, cnt, c * CH_,
                               embB, Ub, bgp, P0, S_ /* unused: no GEMM blocks */);
        }
    }
    hipLaunchKernelGGL(k4a_alpha, dim3(64), dim3(512), 0, stream, out1, wa, alp);
    hipLaunchKernelGGL(k4b_ctx, dim3(64), dim3(512), 0, stream, out2, Wbb, embB, alp, ctx);
    hipLaunchKernelGGL(k4c_out, dim3(64), dim3(128), 0, stream, ctx, Wout, out);
}